// Round 1
// baseline (904.727 us; speedup 1.0000x reference)
//
#include <hip/hip_runtime.h>
#include <stdint.h>

// Problem constants
#define SEQ     1024
#define DMODEL  1024
#define DINNER  2048
#define DPROJ   4480
#define NHEADS  32
#define HEADDIM 64
#define DSTATE  128
// proj column offsets: z=0, x=2048, Bp=4096, Cp=4224, dd_dt=4352, dd_A=4384, trap=4416, ang=4448

typedef __attribute__((ext_vector_type(8))) short short8;
typedef __attribute__((ext_vector_type(4))) float f4;

__device__ __forceinline__ short f2b(float f){
  union { float f; uint32_t u; } v; v.f = f;
  uint32_t r = (v.u + 0x7fffu + ((v.u >> 16) & 1u)) >> 16;
  return (short)(uint16_t)r;
}

__device__ __forceinline__ float softplus_f(float x){
  return x > 20.f ? x : log1pf(__expf(x));
}

// ---- cast fp32 -> bf16 (n multiple of 1024) ----
__global__ __launch_bounds__(256) void cast_kernel(const float* __restrict__ in, short* __restrict__ out){
  int i = (blockIdx.x * 256 + threadIdx.x) * 4;
  f4 v = *(const f4*)(in + i);
  uint32_t lo = (uint32_t)(uint16_t)f2b(v.x) | ((uint32_t)(uint16_t)f2b(v.y) << 16);
  uint32_t hi = (uint32_t)(uint16_t)f2b(v.z) | ((uint32_t)(uint16_t)f2b(v.w) << 16);
  uint2 pk; pk.x = lo; pk.y = hi;
  *(uint2*)(out + i) = pk;
}

// ---- transpose + cast: in[R][C] fp32 -> out[C][R] bf16. grid(C/32, R/32), block(32,8) ----
__global__ __launch_bounds__(256) void transpose_cast(const float* __restrict__ in, short* __restrict__ out,
                                                      int R, int C){
  __shared__ float tile[32][33];
  int bc = blockIdx.x * 32;
  int br = blockIdx.y * 32;
  int tx = threadIdx.x, ty = threadIdx.y;
  #pragma unroll
  for (int i = 0; i < 32; i += 8)
    tile[ty + i][tx] = in[(size_t)(br + ty + i) * C + bc + tx];
  __syncthreads();
  #pragma unroll
  for (int i = 0; i < 32; i += 8)
    out[(size_t)(bc + ty + i) * R + br + tx] = f2b(tile[tx][ty + i]);
}

// ---- bf16 MFMA GEMM: C[M][N] fp32 = A[M][K] @ Bt[N][K], 128x128 tile, BK=32 ----
__global__ __launch_bounds__(256) void gemm_bt(const short* __restrict__ A, const short* __restrict__ Bt,
                                               float* __restrict__ C, int M, int N, int K){
  __shared__ __align__(16) short As[128 * 32];
  __shared__ __align__(16) short Bs[128 * 32];
  const int tid  = threadIdx.x;
  const int wave = tid >> 6;
  const int lane = tid & 63;
  const int m0 = blockIdx.y * 128;
  const int n0 = blockIdx.x * 128;
  const int wm = (wave >> 1) * 64;   // wave's 64-row band
  const int wn = (wave & 1) * 64;    // wave's 64-col band
  const int quad = lane >> 4;        // 0..3
  const int r16  = lane & 15;

  f4 acc[4][4];
  #pragma unroll
  for (int i = 0; i < 4; i++)
    #pragma unroll
    for (int j = 0; j < 4; j++) acc[i][j] = (f4){0.f, 0.f, 0.f, 0.f};

  // staging: slot = tid (+256): row = slot>>2 (0..127), kq = slot&3 -> 8 shorts (16B)
  const int row0 = tid >> 2;
  const int kq   = tid & 3;
  const short* gA0 = A  + (size_t)(m0 + row0) * K + kq * 8;
  const short* gA1 = A  + (size_t)(m0 + row0 + 64) * K + kq * 8;
  const short* gB0 = Bt + (size_t)(n0 + row0) * K + kq * 8;
  const short* gB1 = Bt + (size_t)(n0 + row0 + 64) * K + kq * 8;
  short8* lA0 = (short8*)&As[(size_t)tid * 8];
  short8* lA1 = (short8*)&As[(size_t)(tid + 256) * 8];
  short8* lB0 = (short8*)&Bs[(size_t)tid * 8];
  short8* lB1 = (short8*)&Bs[(size_t)(tid + 256) * 8];

  const int nk = K >> 5;
  for (int kt = 0; kt < nk; ++kt){
    const int ko = kt * 32;
    short8 ra0 = *(const short8*)(gA0 + ko);
    short8 ra1 = *(const short8*)(gA1 + ko);
    short8 rb0 = *(const short8*)(gB0 + ko);
    short8 rb1 = *(const short8*)(gB1 + ko);
    __syncthreads();           // previous iter's reads done
    *lA0 = ra0; *lA1 = ra1; *lB0 = rb0; *lB1 = rb1;
    __syncthreads();           // tile visible
    short8 af[4], bf[4];
    #pragma unroll
    for (int i = 0; i < 4; i++){
      af[i] = *(const short8*)&As[(wm + i * 16 + r16) * 32 + quad * 8];
      bf[i] = *(const short8*)&Bs[(wn + i * 16 + r16) * 32 + quad * 8];
    }
    #pragma unroll
    for (int i = 0; i < 4; i++)
      #pragma unroll
      for (int j = 0; j < 4; j++)
        acc[i][j] = __builtin_amdgcn_mfma_f32_16x16x32_bf16(af[i], bf[j], acc[i][j], 0, 0, 0);
  }

  #pragma unroll
  for (int i = 0; i < 4; i++)
    #pragma unroll
    for (int j = 0; j < 4; j++)
      #pragma unroll
      for (int rr = 0; rr < 4; ++rr){
        int row = m0 + wm + i * 16 + quad * 4 + rr;
        int col = n0 + wn + j * 16 + r16;
        C[(size_t)row * N + col] = acc[i][j][rr];
      }
}

// ---- per-(t,h) scalars: coef[t*32+h] = {a, dt*lam, dt*(1-lam)*a, dt} ----
__global__ __launch_bounds__(256) void prep_kernel(const float* __restrict__ proj,
                                                   const float* __restrict__ dt_bias,
                                                   f4* __restrict__ coef){
  int idx = blockIdx.x * 256 + threadIdx.x;   // 0..32767
  int t = idx >> 5, h = idx & 31;
  const float* row = proj + (size_t)t * DPROJ;
  float dt  = softplus_f(row[4352 + h] + dt_bias[h]);
  float Ah  = -fmaxf(softplus_f(row[4384 + h]), 1e-4f);
  float a   = __expf(Ah * dt);
  float lam = 1.f / (1.f + __expf(-row[4416 + h]));
  f4 c; c.x = a; c.y = dt * lam; c.z = dt * (1.f - lam) * a; c.w = dt;
  coef[idx] = c;
}

// ---- theta cumsum + cos/sin: one thread per (h,k), sequential over t ----
__global__ __launch_bounds__(256) void theta_kernel(const float* __restrict__ proj,
                                                    const f4* __restrict__ coef,
                                                    float* __restrict__ cosb, float* __restrict__ sinb){
  int idx = blockIdx.x * 256 + threadIdx.x;   // 0..1023
  int h = idx >> 5, k = idx & 31;
  float acc = 0.f;
  for (int t = 0; t < SEQ; ++t){
    float ang = proj[(size_t)t * DPROJ + 4448 + k];
    float dt  = coef[t * 32 + h].w;
    acc += ang * dt;
    float s, c;
    __sincosf(acc, &s, &c);
    cosb[(size_t)t * 1024 + h * 32 + k] = c;
    sinb[(size_t)t * 1024 + h * 32 + k] = s;
  }
}

// ---- rmsnorm(Bp/Cp) + per-head bias + rope -> Bh/Ch [t][h][n] ----
__global__ __launch_bounds__(256) void bc_kernel(const float* __restrict__ proj,
                                                 const float* __restrict__ B_bias, const float* __restrict__ C_bias,
                                                 const float* __restrict__ Bn_w, const float* __restrict__ Cn_w,
                                                 const float* __restrict__ cosb, const float* __restrict__ sinb,
                                                 float* __restrict__ Bh, float* __restrict__ Ch){
  int t = blockIdx.x;
  int tid = threadIdx.x;
  __shared__ float vB[128], vC[128];
  __shared__ float red[4];
  int n = tid & 127;
  bool isC = tid >= 128;
  float val = proj[(size_t)t * DPROJ + 4096 + (isC ? 128 : 0) + n];
  float ss = val * val;
  #pragma unroll
  for (int off = 32; off >= 1; off >>= 1) ss += __shfl_down(ss, off);
  int wave = tid >> 6, lane = tid & 63;
  if (lane == 0) red[wave] = ss;
  __syncthreads();
  float rsv = isC ? rsqrtf((red[2] + red[3]) * (1.f / 128.f) + 1e-5f)
                  : rsqrtf((red[0] + red[1]) * (1.f / 128.f) + 1e-5f);
  float nv = val * rsv * (isC ? Cn_w[n] : Bn_w[n]);
  (isC ? vC : vB)[n] = nv;
  __syncthreads();
  const float* bias = isC ? C_bias : B_bias;
  const float* base = isC ? vC : vB;
  float* outp = isC ? Ch : Bh;
  const float* cb = cosb + (size_t)t * 1024;
  const float* sb = sinb + (size_t)t * 1024;
  for (int h = 0; h < 32; ++h){
    float v = base[n] + bias[h * 128 + n];
    float o;
    if (n < 32){
      float v2 = base[n + 32] + bias[h * 128 + n + 32];
      float c = cb[h * 32 + n], s = sb[h * 32 + n];
      o = v * c - v2 * s;
    } else if (n < 64){
      int k = n - 32;
      float v1 = base[k] + bias[h * 128 + k];
      float c = cb[h * 32 + k], s = sb[h * 32 + k];
      o = v1 * s + v * c;
    } else {
      o = v;
    }
    outp[(size_t)t * 4096 + h * 128 + n] = o;
  }
}

// ---- sequential recurrence: 256 blocks = 32 heads x 8 p-splits ----
__global__ __launch_bounds__(256) void scan_kernel(const float* __restrict__ Bh, const float* __restrict__ Ch,
                                                   const float* __restrict__ proj, const f4* __restrict__ coef,
                                                   float* __restrict__ y){
  int head = blockIdx.x >> 3;
  int pblk = blockIdx.x & 7;
  int tid = threadIdx.x;
  int p  = pblk * 8 + (tid >> 5);    // 0..63
  int nb = (tid & 31) * 4;           // 0..124
  const float* Bp = Bh + head * 128 + nb;
  const float* Cp = Ch + head * 128 + nb;
  const float* xp = proj + 2048 + head * 64 + p;
  const f4* cf = coef + head;
  float* yp = y + head * 64 + p;
  f4 h = {0.f, 0.f, 0.f, 0.f}, kp = {0.f, 0.f, 0.f, 0.f};
  float vp = 0.f;
  #pragma unroll 4
  for (int t = 0; t < SEQ; ++t){
    f4 B = *(const f4*)(Bp + (size_t)t * 4096);
    f4 Cv = *(const f4*)(Cp + (size_t)t * 4096);
    float x = xp[(size_t)t * DPROJ];
    f4 cc = cf[t * 32];
    float cx = cc.y * x;
    float cv = cc.z * vp;
    h.x = cc.x * h.x + cx * B.x + cv * kp.x;
    h.y = cc.x * h.y + cx * B.y + cv * kp.y;
    h.z = cc.x * h.z + cx * B.z + cv * kp.z;
    h.w = cc.x * h.w + cx * B.w + cv * kp.w;
    float yv = Cv.x * h.x + Cv.y * h.y + Cv.z * h.z + Cv.w * h.w;
    yv += __shfl_down(yv, 16, 32);
    yv += __shfl_down(yv, 8, 32);
    yv += __shfl_down(yv, 4, 32);
    yv += __shfl_down(yv, 2, 32);
    yv += __shfl_down(yv, 1, 32);
    if ((tid & 31) == 0) yp[(size_t)t * DINNER] = yv;
    kp = B; vp = x;
  }
}

// ---- y = (y + D*x) * silu(z), cast bf16 ----
__global__ __launch_bounds__(256) void post_kernel(const float* __restrict__ y, const float* __restrict__ proj,
                                                   const float* __restrict__ D_par, short* __restrict__ yb){
  int i = (blockIdx.x * 256 + threadIdx.x) * 4;
  int t = i >> 11, d = i & 2047;
  int h = d >> 6;
  f4 yv = *(const f4*)(y + i);
  f4 xv = *(const f4*)(proj + (size_t)t * DPROJ + 2048 + d);
  f4 zv = *(const f4*)(proj + (size_t)t * DPROJ + d);
  float Dp = D_par[h];
  float o0 = (yv.x + Dp * xv.x) * (zv.x / (1.f + __expf(-zv.x)));
  float o1 = (yv.y + Dp * xv.y) * (zv.y / (1.f + __expf(-zv.y)));
  float o2 = (yv.z + Dp * xv.z) * (zv.z / (1.f + __expf(-zv.z)));
  float o3 = (yv.w + Dp * xv.w) * (zv.w / (1.f + __expf(-zv.w)));
  uint32_t lo = (uint32_t)(uint16_t)f2b(o0) | ((uint32_t)(uint16_t)f2b(o1) << 16);
  uint32_t hi = (uint32_t)(uint16_t)f2b(o2) | ((uint32_t)(uint16_t)f2b(o3) << 16);
  uint2 pk; pk.x = lo; pk.y = hi;
  *(uint2*)(yb + i) = pk;
}

extern "C" void kernel_launch(void* const* d_in, const int* in_sizes, int n_in,
                              void* d_out, int out_size, void* d_ws, size_t ws_size,
                              hipStream_t stream){
  const float* u       = (const float*)d_in[0];
  const float* W_in    = (const float*)d_in[1];
  const float* dt_bias = (const float*)d_in[2];
  const float* B_bias  = (const float*)d_in[3];
  const float* C_bias  = (const float*)d_in[4];
  const float* Bn_w    = (const float*)d_in[5];
  const float* Cn_w    = (const float*)d_in[6];
  const float* D_par   = (const float*)d_in[7];
  const float* W_out   = (const float*)d_in[8];
  float* out = (float*)d_out;

  char* ws = (char*)d_ws;
  short* u16   = (short*)(ws + 0);          //  2,097,152 B
  short* WtIn  = (short*)(ws + 2097152);    //  9,175,040 B  [4480][1024] bf16
  short* WtOut = (short*)(ws + 11272192);   //  4,194,304 B  [1024][2048] bf16
  float* proj  = (float*)(ws + 15466496);   // 18,350,080 B  [1024][4480] fp32
  f4*    coef  = (f4*)   (ws + 33816576);   //    524,288 B  [1024*32] {a,c1,c2,dt}
  float* cosb  = (float*)(ws + 34340864);   //  4,194,304 B  [1024][32][32]
  float* sinb  = (float*)(ws + 38535168);   //  4,194,304 B
  float* Bh    = (float*)(ws + 42729472);   // 16,777,216 B  [1024][32][128]
  float* Ch    = (float*)(ws + 59506688);   // 16,777,216 B
  float* ybuf  = (float*)(ws + 76283904);   //  8,388,608 B  [1024][2048]
  short* yb16  = (short*)(ws + 84672512);   //  4,194,304 B  -> total 88,866,816 B

  cast_kernel<<<1024, 256, 0, stream>>>(u, u16);
  transpose_cast<<<dim3(140, 32), dim3(32, 8), 0, stream>>>(W_in, WtIn, 1024, 4480);
  transpose_cast<<<dim3(32, 64), dim3(32, 8), 0, stream>>>(W_out, WtOut, 2048, 1024);
  gemm_bt<<<dim3(35, 8), 256, 0, stream>>>(u16, WtIn, proj, 1024, 4480, 1024);
  prep_kernel<<<128, 256, 0, stream>>>(proj, dt_bias, coef);
  theta_kernel<<<4, 256, 0, stream>>>(proj, coef, cosb, sinb);
  bc_kernel<<<1024, 256, 0, stream>>>(proj, B_bias, C_bias, Bn_w, Cn_w, cosb, sinb, Bh, Ch);
  scan_kernel<<<256, 256, 0, stream>>>(Bh, Ch, proj, coef, ybuf);
  post_kernel<<<2048, 256, 0, stream>>>(ybuf, proj, D_par, yb16);
  gemm_bt<<<dim3(8, 8), 256, 0, stream>>>(yb16, WtOut, out, 1024, 1024, 2048);
}

// Round 2
// 351.209 us; speedup vs baseline: 2.5760x; 2.5760x over previous
//
#include <hip/hip_runtime.h>
#include <stdint.h>

#define SEQ     1024
#define DPROJ   4480
// proj columns: z=0, x=2048, Bp=4096, Cp=4224, dd_dt=4352, dd_A=4384, trap=4416, ang=4448

typedef __attribute__((ext_vector_type(8))) short short8;
typedef __attribute__((ext_vector_type(4))) float f4;

__device__ __forceinline__ short f2b(float f){
  union { float f; uint32_t u; } v; v.f = f;
  uint32_t r = (v.u + 0x7fffu + ((v.u >> 16) & 1u)) >> 16;
  return (short)(uint16_t)r;
}
__device__ __forceinline__ float b2f(uint16_t u){
  union { uint32_t u; float f; } v; v.u = ((uint32_t)u) << 16; return v.f;
}
__device__ __forceinline__ float softplus_f(float x){
  return x > 20.f ? x : log1pf(__expf(x));
}

// ---- cast fp32 -> bf16 ----
__global__ __launch_bounds__(256) void cast_kernel(const float* __restrict__ in, short* __restrict__ out){
  int i = (blockIdx.x * 256 + threadIdx.x) * 4;
  f4 v = *(const f4*)(in + i);
  uint32_t lo = (uint32_t)(uint16_t)f2b(v.x) | ((uint32_t)(uint16_t)f2b(v.y) << 16);
  uint32_t hi = (uint32_t)(uint16_t)f2b(v.z) | ((uint32_t)(uint16_t)f2b(v.w) << 16);
  uint2 pk; pk.x = lo; pk.y = hi;
  *(uint2*)(out + i) = pk;
}

// ---- transpose + cast: out[c][R] = in[r][lda] window (c0..c0+C). grid(C/32, R/32), block(32,8) ----
__global__ __launch_bounds__(256) void transpose_cast(const float* __restrict__ in, short* __restrict__ out,
                                                      int R, int C, int lda, int c0){
  __shared__ float tile[32][33];
  int bc = blockIdx.x * 32;
  int br = blockIdx.y * 32;
  int tx = threadIdx.x, ty = threadIdx.y;
  #pragma unroll
  for (int i = 0; i < 32; i += 8)
    tile[ty + i][tx] = in[(size_t)(br + ty + i) * lda + c0 + bc + tx];
  __syncthreads();
  #pragma unroll
  for (int i = 0; i < 32; i += 8)
    out[(size_t)(bc + ty + i) * R + br + tx] = f2b(tile[tx][ty + i]);
}

// ---- bf16 MFMA GEMM: C[M][N] = A[M][K] @ Bt[N][K]ᵀ, 128x128 tile, BK=32 (verified R1) ----
__global__ __launch_bounds__(256) void gemm_bt(const short* __restrict__ A, const short* __restrict__ Bt,
                                               float* __restrict__ C, int M, int N, int K){
  __shared__ __align__(16) short As[128 * 32];
  __shared__ __align__(16) short Bs[128 * 32];
  const int tid  = threadIdx.x;
  const int wave = tid >> 6;
  const int lane = tid & 63;
  const int m0 = blockIdx.y * 128;
  const int n0 = blockIdx.x * 128;
  const int wm = (wave >> 1) * 64;
  const int wn = (wave & 1) * 64;
  const int quad = lane >> 4;
  const int r16  = lane & 15;

  f4 acc[4][4];
  #pragma unroll
  for (int i = 0; i < 4; i++)
    #pragma unroll
    for (int j = 0; j < 4; j++) acc[i][j] = (f4){0.f, 0.f, 0.f, 0.f};

  const int row0 = tid >> 2;
  const int kq   = tid & 3;
  const short* gA0 = A  + (size_t)(m0 + row0) * K + kq * 8;
  const short* gA1 = A  + (size_t)(m0 + row0 + 64) * K + kq * 8;
  const short* gB0 = Bt + (size_t)(n0 + row0) * K + kq * 8;
  const short* gB1 = Bt + (size_t)(n0 + row0 + 64) * K + kq * 8;
  short8* lA0 = (short8*)&As[(size_t)tid * 8];
  short8* lA1 = (short8*)&As[(size_t)(tid + 256) * 8];
  short8* lB0 = (short8*)&Bs[(size_t)tid * 8];
  short8* lB1 = (short8*)&Bs[(size_t)(tid + 256) * 8];

  const int nk = K >> 5;
  for (int kt = 0; kt < nk; ++kt){
    const int ko = kt * 32;
    short8 ra0 = *(const short8*)(gA0 + ko);
    short8 ra1 = *(const short8*)(gA1 + ko);
    short8 rb0 = *(const short8*)(gB0 + ko);
    short8 rb1 = *(const short8*)(gB1 + ko);
    __syncthreads();
    *lA0 = ra0; *lA1 = ra1; *lB0 = rb0; *lB1 = rb1;
    __syncthreads();
    short8 af[4], bf[4];
    #pragma unroll
    for (int i = 0; i < 4; i++){
      af[i] = *(const short8*)&As[(wm + i * 16 + r16) * 32 + quad * 8];
      bf[i] = *(const short8*)&Bs[(wn + i * 16 + r16) * 32 + quad * 8];
    }
    #pragma unroll
    for (int i = 0; i < 4; i++)
      #pragma unroll
      for (int j = 0; j < 4; j++)
        acc[i][j] = __builtin_amdgcn_mfma_f32_16x16x32_bf16(af[i], bf[j], acc[i][j], 0, 0, 0);
  }

  #pragma unroll
  for (int i = 0; i < 4; i++)
    #pragma unroll
    for (int j = 0; j < 4; j++)
      #pragma unroll
      for (int rr = 0; rr < 4; ++rr){
        int row = m0 + wm + i * 16 + quad * 4 + rr;
        int col = n0 + wn + j * 16 + r16;
        C[(size_t)row * N + col] = acc[i][j][rr];
      }
}

// ---- per-(t,h): coefA[t*32+h] = {la=log a, c1=dt*lam, c2n=dt*(1-lam), dt} ----
__global__ __launch_bounds__(256) void prep_kernel(const float* __restrict__ proj,
                                                   const float* __restrict__ dt_bias,
                                                   f4* __restrict__ coefA){
  int idx = blockIdx.x * 256 + threadIdx.x;
  int t = idx >> 5, h = idx & 31;
  const float* row = proj + (size_t)t * DPROJ;
  float dt  = softplus_f(row[4352 + h] + dt_bias[h]);
  float Ah  = -fmaxf(softplus_f(row[4384 + h]), 1e-4f);
  float lam = 1.f / (1.f + __expf(-row[4416 + h]));
  f4 c; c.x = Ah * dt; c.y = dt * lam; c.z = dt * (1.f - lam); c.w = dt;
  coefA[idx] = c;
}

// ---- per-head parallel prefix scan: Lcum[h][t] = cumsum(la); u2 = c1 + c2n[t+1]; c1 copy ----
__global__ __launch_bounds__(256) void scanL_kernel(const f4* __restrict__ coefA,
                                                    float* __restrict__ Lcum,
                                                    float* __restrict__ u2b,
                                                    float* __restrict__ c1b){
  int h = blockIdx.x;
  int tid = threadIdx.x;
  int t0 = tid * 4;
  float v[4], c1[4], c2n[4];
  #pragma unroll
  for (int i = 0; i < 4; i++){
    f4 cc = coefA[(t0 + i) * 32 + h];
    v[i] = cc.x; c1[i] = cc.y;
  }
  #pragma unroll
  for (int i = 0; i < 4; i++){
    int t = t0 + i;
    c2n[i] = (t < 1023) ? coefA[(t + 1) * 32 + h].z : 0.f;
  }
  v[1] += v[0]; v[2] += v[1]; v[3] += v[2];
  float tot = v[3], sc = tot;
  int lane = tid & 63, wave = tid >> 6;
  #pragma unroll
  for (int off = 1; off < 64; off <<= 1){
    float n = __shfl_up(sc, off, 64);
    if (lane >= off) sc += n;
  }
  __shared__ float wsum[4];
  if (lane == 63) wsum[wave] = sc;
  __syncthreads();
  float base = sc - tot;
  for (int w = 0; w < wave; ++w) base += wsum[w];
  #pragma unroll
  for (int i = 0; i < 4; i++){
    int t = t0 + i;
    Lcum[h * 1024 + t] = base + v[i];
    u2b[h * 1024 + t]  = c1[i] + c2n[i];
    c1b[h * 1024 + t]  = c1[i];
  }
}

// ---- theta cumsum via parallel scan: 1024 blocks = (h,k) ----
__global__ __launch_bounds__(256) void theta2_kernel(const float* __restrict__ proj,
                                                     const f4* __restrict__ coefA,
                                                     float* __restrict__ cosb, float* __restrict__ sinb){
  int h = blockIdx.x >> 5, k = blockIdx.x & 31;
  int tid = threadIdx.x;
  int t0 = tid * 4;
  float v[4];
  #pragma unroll
  for (int i = 0; i < 4; i++){
    int t = t0 + i;
    v[i] = proj[(size_t)t * DPROJ + 4448 + k] * coefA[t * 32 + h].w;
  }
  v[1] += v[0]; v[2] += v[1]; v[3] += v[2];
  float tot = v[3], sc = tot;
  int lane = tid & 63, wave = tid >> 6;
  #pragma unroll
  for (int off = 1; off < 64; off <<= 1){
    float n = __shfl_up(sc, off, 64);
    if (lane >= off) sc += n;
  }
  __shared__ float wsum[4];
  if (lane == 63) wsum[wave] = sc;
  __syncthreads();
  float base = sc - tot;
  for (int w = 0; w < wave; ++w) base += wsum[w];
  #pragma unroll
  for (int i = 0; i < 4; i++){
    float th = base + v[i];
    float s, c;
    __sincosf(th, &s, &c);
    int t = t0 + i;
    cosb[(size_t)t * 1024 + h * 32 + k] = c;
    sinb[(size_t)t * 1024 + h * 32 + k] = s;
  }
}

// ---- rmsnorm + bias + rope -> Bb/Cb bf16 [t][h*128+n] ----
__global__ __launch_bounds__(256) void bc_kernel(const float* __restrict__ proj,
                                                 const float* __restrict__ B_bias, const float* __restrict__ C_bias,
                                                 const float* __restrict__ Bn_w, const float* __restrict__ Cn_w,
                                                 const float* __restrict__ cosb, const float* __restrict__ sinb,
                                                 short* __restrict__ Bb, short* __restrict__ Cb){
  int t = blockIdx.x;
  int tid = threadIdx.x;
  __shared__ float vB[128], vC[128];
  __shared__ float red[4];
  int n = tid & 127;
  bool isC = tid >= 128;
  float val = proj[(size_t)t * DPROJ + 4096 + (isC ? 128 : 0) + n];
  float ss = val * val;
  #pragma unroll
  for (int off = 32; off >= 1; off >>= 1) ss += __shfl_down(ss, off);
  int wave = tid >> 6, lane = tid & 63;
  if (lane == 0) red[wave] = ss;
  __syncthreads();
  float rsv = isC ? rsqrtf((red[2] + red[3]) * (1.f / 128.f) + 1e-5f)
                  : rsqrtf((red[0] + red[1]) * (1.f / 128.f) + 1e-5f);
  float nv = val * rsv * (isC ? Cn_w[n] : Bn_w[n]);
  (isC ? vC : vB)[n] = nv;
  __syncthreads();
  const float* bias = isC ? C_bias : B_bias;
  const float* base = isC ? vC : vB;
  short* outp = isC ? Cb : Bb;
  const float* cb = cosb + (size_t)t * 1024;
  const float* sb = sinb + (size_t)t * 1024;
  for (int h = 0; h < 32; ++h){
    float v = base[n] + bias[h * 128 + n];
    float o;
    if (n < 32){
      float v2 = base[n + 32] + bias[h * 128 + n + 32];
      float c = cb[h * 32 + n], s = sb[h * 32 + n];
      o = v * c - v2 * s;
    } else if (n < 64){
      int k = n - 32;
      float v1 = base[k] + bias[h * 128 + k];
      float c = cb[h * 32 + k], s = sb[h * 32 + k];
      o = v1 * s + v * c;
    } else {
      o = v;
    }
    outp[(size_t)t * 4096 + h * 128 + n] = f2b(o);
  }
}

// ---- per-chunk state contribution: Hpart[h][c][p][n] = sum_s exp(Lend-L[s])*u2[s]*x[s][p]*B[s][n] ----
__global__ __launch_bounds__(256) void hpart_kernel(const float* __restrict__ proj, const short* __restrict__ Bb,
                                                    const float* __restrict__ Lcum, const float* __restrict__ u2b,
                                                    short* __restrict__ Hpart){
  int h = blockIdx.x >> 3, c = blockIdx.x & 7;
  int t0 = c * 128;
  int tid = threadIdx.x;
  __shared__ float w[128];
  if (tid < 128){
    float Lend = Lcum[h * 1024 + t0 + 127];
    w[tid] = __expf(Lend - Lcum[h * 1024 + t0 + tid]) * u2b[h * 1024 + t0 + tid];
  }
  __syncthreads();
  int p = tid & 63, nq = tid >> 6;
  f4 acc[8];
  #pragma unroll
  for (int k = 0; k < 8; k++) acc[k] = (f4){0.f, 0.f, 0.f, 0.f};
  for (int s = 0; s < 128; ++s){
    float xw = proj[(size_t)(t0 + s) * DPROJ + 2048 + h * 64 + p] * w[s];
    const ushort* Bp = (const ushort*)(Bb + (size_t)(t0 + s) * 4096 + h * 128 + nq * 32);
    #pragma unroll
    for (int k = 0; k < 8; k++){
      ushort4 b4 = *(const ushort4*)(Bp + k * 4);
      acc[k].x += xw * b2f(b4.x);
      acc[k].y += xw * b2f(b4.y);
      acc[k].z += xw * b2f(b4.z);
      acc[k].w += xw * b2f(b4.w);
    }
  }
  short* out = Hpart + ((size_t)(h * 8 + c)) * 8192 + p * 128 + nq * 32;
  #pragma unroll
  for (int k = 0; k < 8; k++){
    short4 o; o.x = f2b(acc[k].x); o.y = f2b(acc[k].y); o.z = f2b(acc[k].z); o.w = f2b(acc[k].w);
    *(short4*)(out + k * 4) = o;
  }
}

// ---- 8-step state prefix: Hused[h][c] = H̃_{c-1} (bf16) ----
__global__ __launch_bounds__(256) void hscan_kernel(const short* __restrict__ Hpart,
                                                    const float* __restrict__ Lcum,
                                                    short* __restrict__ Hused){
  int idx = blockIdx.x * 256 + threadIdx.x;
  int h = idx >> 13, rem = idx & 8191;
  float acc = 0.f;
  float Lprev = 0.f;
  #pragma unroll
  for (int c = 0; c < 8; c++){
    Hused[((size_t)(h * 8 + c)) * 8192 + rem] = f2b(acc);
    float Lend = Lcum[h * 1024 + c * 128 + 127];
    float dec = __expf(Lend - Lprev);
    acc = dec * acc + b2f((uint16_t)Hpart[((size_t)(h * 8 + c)) * 8192 + rem]);
    Lprev = Lend;
  }
}

// ---- chunked dual form: per (h,c): S=C@Bᵀ -> weight -> Y = G@X + diag(einter)·(C@H̃ᵀ) ----
#define GS 144   // Gt LDS stride (shorts): 288B rows, 16B-aligned, breaks bank conflicts
__global__ __launch_bounds__(256) void chunky_kernel(const short* __restrict__ Cb, const short* __restrict__ Bbg,
                                                     const short* __restrict__ xTb, const short* __restrict__ Hused,
                                                     const float* __restrict__ Lcum, const float* __restrict__ u2b,
                                                     const float* __restrict__ c1b,
                                                     float* __restrict__ ybuf){
  int h = blockIdx.x >> 3, c = blockIdx.x & 7;
  int t0 = c * 128;
  __shared__ __align__(16) short Gt[128 * GS];
  __shared__ float Lc[128], u2v[128], c1v[128];
  int tid = threadIdx.x;
  if (tid < 128){
    Lc[tid]  = Lcum[h * 1024 + t0 + tid];
    u2v[tid] = u2b[h * 1024 + t0 + tid];
    c1v[tid] = c1b[h * 1024 + t0 + tid];
  }
  float Lprev = (c > 0) ? Lcum[h * 1024 + t0 - 1] : 0.f;
  int wave = tid >> 6, lane = tid & 63, quad = lane >> 4, r16 = lane & 15;
  int wm = (wave >> 1) * 64, wn = (wave & 1) * 64;

  // Phase 1: S = C @ Bᵀ (contraction over n=128), fragments straight from global
  f4 acc[4][4];
  #pragma unroll
  for (int i = 0; i < 4; i++)
    #pragma unroll
    for (int j = 0; j < 4; j++) acc[i][j] = (f4){0.f, 0.f, 0.f, 0.f};
  #pragma unroll
  for (int kk = 0; kk < 4; ++kk){
    short8 af[4], bf[4];
    #pragma unroll
    for (int i = 0; i < 4; i++)
      af[i] = *(const short8*)(Cb + (size_t)(t0 + wm + i * 16 + r16) * 4096 + h * 128 + kk * 32 + quad * 8);
    #pragma unroll
    for (int j = 0; j < 4; j++)
      bf[j] = *(const short8*)(Bbg + (size_t)(t0 + wn + j * 16 + r16) * 4096 + h * 128 + kk * 32 + quad * 8);
    #pragma unroll
    for (int i = 0; i < 4; i++)
      #pragma unroll
      for (int j = 0; j < 4; j++)
        acc[i][j] = __builtin_amdgcn_mfma_f32_16x16x32_bf16(af[i], bf[j], acc[i][j], 0, 0, 0);
  }
  __syncthreads();   // Lc/u2v/c1v visible

  // Phase 2: weight + mask, pack G to LDS (bf16)
  #pragma unroll
  for (int i = 0; i < 4; i++){
    #pragma unroll
    for (int rr = 0; rr < 4; ++rr){
      int trow = wm + i * 16 + quad * 4 + rr;
      float Lt = Lc[trow];
      #pragma unroll
      for (int j = 0; j < 4; j++){
        int scol = wn + j * 16 + r16;
        float g = 0.f;
        if (scol <= trow){
          float wcoef = (scol == trow) ? c1v[scol] : u2v[scol];
          g = acc[i][j][rr] * wcoef * __expf(Lt - Lc[scol]);
        }
        Gt[trow * GS + scol] = f2b(g);
      }
    }
  }
  __syncthreads();

  // Phase 3: Y1 = G @ X (K=s), Y2 = C @ H̃ᵀ (K=n); wave covers 32 t-rows x 64 p-cols
  f4 accY[2][4], accZ[2][4];
  #pragma unroll
  for (int i = 0; i < 2; i++)
    #pragma unroll
    for (int j = 0; j < 4; j++){ accY[i][j] = (f4){0.f,0.f,0.f,0.f}; accZ[i][j] = (f4){0.f,0.f,0.f,0.f}; }
  int m0 = wave * 32;
  #pragma unroll
  for (int kk = 0; kk < 4; ++kk){
    short8 ag[2], ac[2], bx[4], bh[4];
    #pragma unroll
    for (int i = 0; i < 2; i++){
      ag[i] = *(const short8*)&Gt[(m0 + i * 16 + r16) * GS + kk * 32 + quad * 8];
      ac[i] = *(const short8*)(Cb + (size_t)(t0 + m0 + i * 16 + r16) * 4096 + h * 128 + kk * 32 + quad * 8);
    }
    #pragma unroll
    for (int j = 0; j < 4; j++){
      bx[j] = *(const short8*)(xTb + (size_t)(h * 64 + j * 16 + r16) * 1024 + t0 + kk * 32 + quad * 8);
      bh[j] = *(const short8*)(Hused + ((size_t)(h * 8 + c) * 64 + j * 16 + r16) * 128 + kk * 32 + quad * 8);
    }
    #pragma unroll
    for (int i = 0; i < 2; i++)
      #pragma unroll
      for (int j = 0; j < 4; j++){
        accY[i][j] = __builtin_amdgcn_mfma_f32_16x16x32_bf16(ag[i], bx[j], accY[i][j], 0, 0, 0);
        accZ[i][j] = __builtin_amdgcn_mfma_f32_16x16x32_bf16(ac[i], bh[j], accZ[i][j], 0, 0, 0);
      }
  }
  #pragma unroll
  for (int i = 0; i < 2; i++)
    #pragma unroll
    for (int rr = 0; rr < 4; ++rr){
      int trow = m0 + i * 16 + quad * 4 + rr;
      float ei = __expf(Lc[trow] - Lprev);
      #pragma unroll
      for (int j = 0; j < 4; j++){
        int p = j * 16 + r16;
        ybuf[(size_t)(t0 + trow) * 2048 + h * 64 + p] = accY[i][j][rr] + ei * accZ[i][j][rr];
      }
    }
}

// ---- y = (y + D*x) * silu(z), cast bf16 ----
__global__ __launch_bounds__(256) void post_kernel(const float* __restrict__ y, const float* __restrict__ proj,
                                                   const float* __restrict__ D_par, short* __restrict__ yb){
  int i = (blockIdx.x * 256 + threadIdx.x) * 4;
  int t = i >> 11, d = i & 2047;
  int h = d >> 6;
  f4 yv = *(const f4*)(y + i);
  f4 xv = *(const f4*)(proj + (size_t)t * DPROJ + 2048 + d);
  f4 zv = *(const f4*)(proj + (size_t)t * DPROJ + d);
  float Dp = D_par[h];
  float o0 = (yv.x + Dp * xv.x) * (zv.x / (1.f + __expf(-zv.x)));
  float o1 = (yv.y + Dp * xv.y) * (zv.y / (1.f + __expf(-zv.y)));
  float o2 = (yv.z + Dp * xv.z) * (zv.z / (1.f + __expf(-zv.z)));
  float o3 = (yv.w + Dp * xv.w) * (zv.w / (1.f + __expf(-zv.w)));
  uint32_t lo = (uint32_t)(uint16_t)f2b(o0) | ((uint32_t)(uint16_t)f2b(o1) << 16);
  uint32_t hi = (uint32_t)(uint16_t)f2b(o2) | ((uint32_t)(uint16_t)f2b(o3) << 16);
  uint2 pk; pk.x = lo; pk.y = hi;
  *(uint2*)(yb + i) = pk;
}

extern "C" void kernel_launch(void* const* d_in, const int* in_sizes, int n_in,
                              void* d_out, int out_size, void* d_ws, size_t ws_size,
                              hipStream_t stream){
  const float* u       = (const float*)d_in[0];
  const float* W_in    = (const float*)d_in[1];
  const float* dt_bias = (const float*)d_in[2];
  const float* B_bias  = (const float*)d_in[3];
  const float* C_bias  = (const float*)d_in[4];
  const float* Bn_w    = (const float*)d_in[5];
  const float* Cn_w    = (const float*)d_in[6];
  const float* D_par   = (const float*)d_in[7];
  const float* W_out   = (const float*)d_in[8];
  float* out = (float*)d_out;

  char* ws = (char*)d_ws;
  short* u16   = (short*)(ws + 0);          //  2,097,152
  short* WtIn  = (short*)(ws + 2097152);    //  9,175,040  [4480][1024] bf16
  short* WtOut = (short*)(ws + 11272192);   //  4,194,304  [1024][2048] bf16
  float* proj  = (float*)(ws + 15466496);   // 18,350,080  [1024][4480] fp32
  f4*    coefA = (f4*)   (ws + 33816576);   //    524,288  [1024*32] {la,c1,c2n,dt}
  float* cosb  = (float*)(ws + 34340864);   //  4,194,304  [1024][1024]
  float* sinb  = (float*)(ws + 38535168);   //  4,194,304
  short* Bb    = (short*)(ws + 42729472);   //  8,388,608  [1024][4096] bf16
  short* Cb    = (short*)(ws + 51118080);   //  8,388,608
  short* xTb   = (short*)(ws + 59506688);   //  4,194,304  [2048][1024] bf16
  float* Lcum  = (float*)(ws + 63700992);   //    131,072  [32][1024]
  float* u2b   = (float*)(ws + 63832064);   //    131,072
  float* c1b   = (float*)(ws + 63963136);   //    131,072
  short* Hpart = (short*)(ws + 64094208);   //  4,194,304  [32][8][64][128] bf16
  short* Hused = (short*)(ws + 68288512);   //  4,194,304
  float* ybuf  = (float*)(ws + 72482816);   //  8,388,608  [1024][2048]
  short* yb16  = (short*)(ws + 80871424);   //  4,194,304  -> total 85,065,728 B

  cast_kernel<<<1024, 256, 0, stream>>>(u, u16);
  transpose_cast<<<dim3(140, 32), dim3(32, 8), 0, stream>>>(W_in, WtIn, 1024, 4480, 4480, 0);
  transpose_cast<<<dim3(32, 64), dim3(32, 8), 0, stream>>>(W_out, WtOut, 2048, 1024, 1024, 0);
  gemm_bt<<<dim3(35, 8), 256, 0, stream>>>(u16, WtIn, proj, 1024, 4480, 1024);
  prep_kernel<<<128, 256, 0, stream>>>(proj, dt_bias, coefA);
  scanL_kernel<<<32, 256, 0, stream>>>(coefA, Lcum, u2b, c1b);
  theta2_kernel<<<1024, 256, 0, stream>>>(proj, coefA, cosb, sinb);
  bc_kernel<<<1024, 256, 0, stream>>>(proj, B_bias, C_bias, Bn_w, Cn_w, cosb, sinb, Bb, Cb);
  transpose_cast<<<dim3(64, 32), dim3(32, 8), 0, stream>>>(proj, xTb, 1024, 2048, 4480, 2048);
  hpart_kernel<<<256, 256, 0, stream>>>(proj, Bb, Lcum, u2b, Hpart);
  hscan_kernel<<<1024, 256, 0, stream>>>(Hpart, Lcum, Hused);
  chunky_kernel<<<256, 256, 0, stream>>>(Cb, Bb, xTb, Hused, Lcum, u2b, c1b, ybuf);
  post_kernel<<<2048, 256, 0, stream>>>(ybuf, proj, D_par, yb16);
  gemm_bt<<<dim3(8, 8), 256, 0, stream>>>(yb16, WtOut, out, 1024, 1024, 2048);
}

// Round 3
// 266.915 us; speedup vs baseline: 3.3896x; 1.3158x over previous
//
#include <hip/hip_runtime.h>
#include <stdint.h>

#define SEQ     1024
#define DPROJ   4480
// proj columns: z=0, x=2048, Bp=4096, Cp=4224, dd_dt=4352, dd_A=4384, trap=4416, ang=4448

typedef __attribute__((ext_vector_type(8))) short short8;
typedef __attribute__((ext_vector_type(4))) float f4;

__device__ __forceinline__ short f2b(float f){
  union { float f; uint32_t u; } v; v.f = f;
  uint32_t r = (v.u + 0x7fffu + ((v.u >> 16) & 1u)) >> 16;
  return (short)(uint16_t)r;
}
__device__ __forceinline__ float b2f(uint16_t u){
  union { uint32_t u; float f; } v; v.u = ((uint32_t)u) << 16; return v.f;
}
__device__ __forceinline__ uint32_t pack2(float lo, float hi){
  return (uint32_t)(uint16_t)f2b(lo) | ((uint32_t)(uint16_t)f2b(hi) << 16);
}
__device__ __forceinline__ float softplus_f(float x){
  return x > 20.f ? x : log1pf(__expf(x));
}

// ---- cast fp32 -> bf16 ----
__global__ __launch_bounds__(256) void cast_kernel(const float* __restrict__ in, short* __restrict__ out){
  int i = (blockIdx.x * 256 + threadIdx.x) * 4;
  f4 v = *(const f4*)(in + i);
  uint32_t lo = (uint32_t)(uint16_t)f2b(v.x) | ((uint32_t)(uint16_t)f2b(v.y) << 16);
  uint32_t hi = (uint32_t)(uint16_t)f2b(v.z) | ((uint32_t)(uint16_t)f2b(v.w) << 16);
  uint2 pk; pk.x = lo; pk.y = hi;
  *(uint2*)(out + i) = pk;
}

// ---- transpose + cast: out[c][R] = in[r][lda] window (c0..c0+C). grid(C/32, R/32), block(32,8) ----
__global__ __launch_bounds__(256) void transpose_cast(const float* __restrict__ in, short* __restrict__ out,
                                                      int R, int C, int lda, int c0){
  __shared__ float tile[32][33];
  int bc = blockIdx.x * 32;
  int br = blockIdx.y * 32;
  int tx = threadIdx.x, ty = threadIdx.y;
  #pragma unroll
  for (int i = 0; i < 32; i += 8)
    tile[ty + i][tx] = in[(size_t)(br + ty + i) * lda + c0 + bc + tx];
  __syncthreads();
  #pragma unroll
  for (int i = 0; i < 32; i += 8)
    out[(size_t)(bc + ty + i) * R + br + tx] = f2b(tile[tx][ty + i]);
}

// ---- bf16 MFMA GEMM: C[M][N] = A[M][K] @ Bt[N][K]ᵀ, 128x128 tile, BK=32 (verified R1) ----
__global__ __launch_bounds__(256) void gemm_bt(const short* __restrict__ A, const short* __restrict__ Bt,
                                               float* __restrict__ C, int M, int N, int K){
  __shared__ __align__(16) short As[128 * 32];
  __shared__ __align__(16) short Bs[128 * 32];
  const int tid  = threadIdx.x;
  const int wave = tid >> 6;
  const int lane = tid & 63;
  const int m0 = blockIdx.y * 128;
  const int n0 = blockIdx.x * 128;
  const int wm = (wave >> 1) * 64;
  const int wn = (wave & 1) * 64;
  const int quad = lane >> 4;
  const int r16  = lane & 15;

  f4 acc[4][4];
  #pragma unroll
  for (int i = 0; i < 4; i++)
    #pragma unroll
    for (int j = 0; j < 4; j++) acc[i][j] = (f4){0.f, 0.f, 0.f, 0.f};

  const int row0 = tid >> 2;
  const int kq   = tid & 3;
  const short* gA0 = A  + (size_t)(m0 + row0) * K + kq * 8;
  const short* gA1 = A  + (size_t)(m0 + row0 + 64) * K + kq * 8;
  const short* gB0 = Bt + (size_t)(n0 + row0) * K + kq * 8;
  const short* gB1 = Bt + (size_t)(n0 + row0 + 64) * K + kq * 8;
  short8* lA0 = (short8*)&As[(size_t)tid * 8];
  short8* lA1 = (short8*)&As[(size_t)(tid + 256) * 8];
  short8* lB0 = (short8*)&Bs[(size_t)tid * 8];
  short8* lB1 = (short8*)&Bs[(size_t)(tid + 256) * 8];

  const int nk = K >> 5;
  for (int kt = 0; kt < nk; ++kt){
    const int ko = kt * 32;
    short8 ra0 = *(const short8*)(gA0 + ko);
    short8 ra1 = *(const short8*)(gA1 + ko);
    short8 rb0 = *(const short8*)(gB0 + ko);
    short8 rb1 = *(const short8*)(gB1 + ko);
    __syncthreads();
    *lA0 = ra0; *lA1 = ra1; *lB0 = rb0; *lB1 = rb1;
    __syncthreads();
    short8 af[4], bf[4];
    #pragma unroll
    for (int i = 0; i < 4; i++){
      af[i] = *(const short8*)&As[(wm + i * 16 + r16) * 32 + quad * 8];
      bf[i] = *(const short8*)&Bs[(wn + i * 16 + r16) * 32 + quad * 8];
    }
    #pragma unroll
    for (int i = 0; i < 4; i++)
      #pragma unroll
      for (int j = 0; j < 4; j++)
        acc[i][j] = __builtin_amdgcn_mfma_f32_16x16x32_bf16(af[i], bf[j], acc[i][j], 0, 0, 0);
  }

  #pragma unroll
  for (int i = 0; i < 4; i++)
    #pragma unroll
    for (int j = 0; j < 4; j++)
      #pragma unroll
      for (int rr = 0; rr < 4; ++rr){
        int row = m0 + wm + i * 16 + quad * 4 + rr;
        int col = n0 + wn + j * 16 + r16;
        C[(size_t)row * N + col] = acc[i][j][rr];
      }
}

// ---- per-(t,h): coefA[t*32+h] = {la=log a, c1=dt*lam, c2n=dt*(1-lam), dt} ----
__global__ __launch_bounds__(256) void prep_kernel(const float* __restrict__ proj,
                                                   const float* __restrict__ dt_bias,
                                                   f4* __restrict__ coefA){
  int idx = blockIdx.x * 256 + threadIdx.x;
  int t = idx >> 5, h = idx & 31;
  const float* row = proj + (size_t)t * DPROJ;
  float dt  = softplus_f(row[4352 + h] + dt_bias[h]);
  float Ah  = -fmaxf(softplus_f(row[4384 + h]), 1e-4f);
  float lam = 1.f / (1.f + __expf(-row[4416 + h]));
  f4 c; c.x = Ah * dt; c.y = dt * lam; c.z = dt * (1.f - lam); c.w = dt;
  coefA[idx] = c;
}

// ---- per-head parallel prefix scan: Lcum[h][t] = cumsum(la); u2 = c1 + c2n[t+1]; c1 copy ----
__global__ __launch_bounds__(256) void scanL_kernel(const f4* __restrict__ coefA,
                                                    float* __restrict__ Lcum,
                                                    float* __restrict__ u2b,
                                                    float* __restrict__ c1b){
  int h = blockIdx.x;
  int tid = threadIdx.x;
  int t0 = tid * 4;
  float v[4], c1[4], c2n[4];
  #pragma unroll
  for (int i = 0; i < 4; i++){
    f4 cc = coefA[(t0 + i) * 32 + h];
    v[i] = cc.x; c1[i] = cc.y;
  }
  #pragma unroll
  for (int i = 0; i < 4; i++){
    int t = t0 + i;
    c2n[i] = (t < 1023) ? coefA[(t + 1) * 32 + h].z : 0.f;
  }
  v[1] += v[0]; v[2] += v[1]; v[3] += v[2];
  float tot = v[3], sc = tot;
  int lane = tid & 63, wave = tid >> 6;
  #pragma unroll
  for (int off = 1; off < 64; off <<= 1){
    float n = __shfl_up(sc, off, 64);
    if (lane >= off) sc += n;
  }
  __shared__ float wsum[4];
  if (lane == 63) wsum[wave] = sc;
  __syncthreads();
  float base = sc - tot;
  for (int w = 0; w < wave; ++w) base += wsum[w];
  #pragma unroll
  for (int i = 0; i < 4; i++){
    int t = t0 + i;
    Lcum[h * 1024 + t] = base + v[i];
    u2b[h * 1024 + t]  = c1[i] + c2n[i];
    c1b[h * 1024 + t]  = c1[i];
  }
}

// ---- theta cumsum via parallel scan: 1024 blocks = (h,k) ----
__global__ __launch_bounds__(256) void theta2_kernel(const float* __restrict__ proj,
                                                     const f4* __restrict__ coefA,
                                                     float* __restrict__ cosb, float* __restrict__ sinb){
  int h = blockIdx.x >> 5, k = blockIdx.x & 31;
  int tid = threadIdx.x;
  int t0 = tid * 4;
  float v[4];
  #pragma unroll
  for (int i = 0; i < 4; i++){
    int t = t0 + i;
    v[i] = proj[(size_t)t * DPROJ + 4448 + k] * coefA[t * 32 + h].w;
  }
  v[1] += v[0]; v[2] += v[1]; v[3] += v[2];
  float tot = v[3], sc = tot;
  int lane = tid & 63, wave = tid >> 6;
  #pragma unroll
  for (int off = 1; off < 64; off <<= 1){
    float n = __shfl_up(sc, off, 64);
    if (lane >= off) sc += n;
  }
  __shared__ float wsum[4];
  if (lane == 63) wsum[wave] = sc;
  __syncthreads();
  float base = sc - tot;
  for (int w = 0; w < wave; ++w) base += wsum[w];
  #pragma unroll
  for (int i = 0; i < 4; i++){
    float th = base + v[i];
    float s, c;
    __sincosf(th, &s, &c);
    int t = t0 + i;
    cosb[(size_t)t * 1024 + h * 32 + k] = c;
    sinb[(size_t)t * 1024 + h * 32 + k] = s;
  }
}

// ---- rmsnorm + bias + rope -> Bb/Cb bf16 [t][h*128+n] ----
__global__ __launch_bounds__(256) void bc_kernel(const float* __restrict__ proj,
                                                 const float* __restrict__ B_bias, const float* __restrict__ C_bias,
                                                 const float* __restrict__ Bn_w, const float* __restrict__ Cn_w,
                                                 const float* __restrict__ cosb, const float* __restrict__ sinb,
                                                 short* __restrict__ Bb, short* __restrict__ Cb){
  int t = blockIdx.x;
  int tid = threadIdx.x;
  __shared__ float vB[128], vC[128];
  __shared__ float red[4];
  int n = tid & 127;
  bool isC = tid >= 128;
  float val = proj[(size_t)t * DPROJ + 4096 + (isC ? 128 : 0) + n];
  float ss = val * val;
  #pragma unroll
  for (int off = 32; off >= 1; off >>= 1) ss += __shfl_down(ss, off);
  int wave = tid >> 6, lane = tid & 63;
  if (lane == 0) red[wave] = ss;
  __syncthreads();
  float rsv = isC ? rsqrtf((red[2] + red[3]) * (1.f / 128.f) + 1e-5f)
                  : rsqrtf((red[0] + red[1]) * (1.f / 128.f) + 1e-5f);
  float nv = val * rsv * (isC ? Cn_w[n] : Bn_w[n]);
  (isC ? vC : vB)[n] = nv;
  __syncthreads();
  const float* bias = isC ? C_bias : B_bias;
  const float* base = isC ? vC : vB;
  short* outp = isC ? Cb : Bb;
  const float* cb = cosb + (size_t)t * 1024;
  const float* sb = sinb + (size_t)t * 1024;
  for (int h = 0; h < 32; ++h){
    float v = base[n] + bias[h * 128 + n];
    float o;
    if (n < 32){
      float v2 = base[n + 32] + bias[h * 128 + n + 32];
      float c = cb[h * 32 + n], s = sb[h * 32 + n];
      o = v * c - v2 * s;
    } else if (n < 64){
      int k = n - 32;
      float v1 = base[k] + bias[h * 128 + k];
      float c = cb[h * 32 + k], s = sb[h * 32 + k];
      o = v1 * s + v * c;
    } else {
      o = v;
    }
    outp[(size_t)t * 4096 + h * 128 + n] = f2b(o);
  }
}

// ---- per-chunk state contribution, MFMA form:
// Hpart[h][c][p][n] = sum_s xT[p][s] * (w[s]*B[s][n]),  w[s]=exp(Lend-L[s])*u2[s]
// M=p(64) from xTb (global, contiguous s), N=n(128) via per-lane bf16 gather from Bb, K=s(128).
__global__ __launch_bounds__(256) void hpart_kernel(const short* __restrict__ xTb, const short* __restrict__ Bb,
                                                    const float* __restrict__ Lcum, const float* __restrict__ u2b,
                                                    short* __restrict__ Hpart){
  int h = blockIdx.x >> 3, c = blockIdx.x & 7;
  int t0 = c * 128;
  int tid = threadIdx.x;
  __shared__ float wS[128];
  if (tid < 128){
    float Lend = Lcum[h * 1024 + t0 + 127];
    wS[tid] = __expf(Lend - Lcum[h * 1024 + t0 + tid]) * u2b[h * 1024 + t0 + tid];
  }
  __syncthreads();
  int wave = tid >> 6, lane = tid & 63, quad = lane >> 4, r16 = lane & 15;
  int n0 = wave * 32;                    // wave's 32-wide n band
  f4 acc[4][2];
  #pragma unroll
  for (int i = 0; i < 4; i++)
    #pragma unroll
    for (int j = 0; j < 2; j++) acc[i][j] = (f4){0.f, 0.f, 0.f, 0.f};

  const ushort* Bh = (const ushort*)Bb + (size_t)t0 * 4096 + h * 128;  // [s][4096] window
  #pragma unroll
  for (int kk = 0; kk < 4; ++kk){
    int sb = kk * 32 + quad * 8;         // this lane's 8 s-values
    // A fragments: xT rows p, contiguous s
    short8 af[4];
    #pragma unroll
    for (int i = 0; i < 4; i++){
      int p = i * 16 + r16;
      af[i] = *(const short8*)(xTb + (size_t)(h * 64 + p) * 1024 + t0 + sb);
    }
    // weights for this lane's 8 s values (LDS broadcast within quad)
    float wv[8];
    #pragma unroll
    for (int jj = 0; jj < 8; jj++) wv[jj] = wS[sb + jj];
    // B fragments: gather B[s][n]*w[s] for n = n0 + j*16 + r16
    short8 bfr[2];
    #pragma unroll
    for (int j = 0; j < 2; j++){
      int n = n0 + j * 16 + r16;
      float e[8];
      #pragma unroll
      for (int jj = 0; jj < 8; jj++)
        e[jj] = b2f(Bh[(size_t)(sb + jj) * 4096 + n]) * wv[jj];
      union { short8 s; uint32_t u[4]; } fr;
      #pragma unroll
      for (int q = 0; q < 4; q++) fr.u[q] = pack2(e[2 * q], e[2 * q + 1]);
      bfr[j] = fr.s;
    }
    #pragma unroll
    for (int i = 0; i < 4; i++)
      #pragma unroll
      for (int j = 0; j < 2; j++)
        acc[i][j] = __builtin_amdgcn_mfma_f32_16x16x32_bf16(af[i], bfr[j], acc[i][j], 0, 0, 0);
  }

  short* out = Hpart + ((size_t)(h * 8 + c)) * 8192;
  #pragma unroll
  for (int i = 0; i < 4; i++)
    #pragma unroll
    for (int rr = 0; rr < 4; ++rr){
      int p = i * 16 + quad * 4 + rr;
      #pragma unroll
      for (int j = 0; j < 2; j++){
        int n = n0 + j * 16 + r16;
        out[p * 128 + n] = f2b(acc[i][j][rr]);
      }
    }
}

// ---- 8-step state prefix: Hused[h][c] = H̃_{c-1} (bf16) ----
__global__ __launch_bounds__(256) void hscan_kernel(const short* __restrict__ Hpart,
                                                    const float* __restrict__ Lcum,
                                                    short* __restrict__ Hused){
  int idx = blockIdx.x * 256 + threadIdx.x;
  int h = idx >> 13, rem = idx & 8191;
  float acc = 0.f;
  float Lprev = 0.f;
  #pragma unroll
  for (int c = 0; c < 8; c++){
    Hused[((size_t)(h * 8 + c)) * 8192 + rem] = f2b(acc);
    float Lend = Lcum[h * 1024 + c * 128 + 127];
    float dec = __expf(Lend - Lprev);
    acc = dec * acc + b2f((uint16_t)Hpart[((size_t)(h * 8 + c)) * 8192 + rem]);
    Lprev = Lend;
  }
}

// ---- chunked dual form: per (h,c): S=C@Bᵀ -> weight -> Y = G@X + diag(einter)·(C@H̃ᵀ) ----
#define GS 144   // Gt LDS stride (shorts): 288B rows, 16B-aligned, breaks bank conflicts
__global__ __launch_bounds__(256) void chunky_kernel(const short* __restrict__ Cb, const short* __restrict__ Bbg,
                                                     const short* __restrict__ xTb, const short* __restrict__ Hused,
                                                     const float* __restrict__ Lcum, const float* __restrict__ u2b,
                                                     const float* __restrict__ c1b,
                                                     float* __restrict__ ybuf){
  int h = blockIdx.x >> 3, c = blockIdx.x & 7;
  int t0 = c * 128;
  __shared__ __align__(16) short Gt[128 * GS];
  __shared__ float Lc[128], u2v[128], c1v[128];
  int tid = threadIdx.x;
  if (tid < 128){
    Lc[tid]  = Lcum[h * 1024 + t0 + tid];
    u2v[tid] = u2b[h * 1024 + t0 + tid];
    c1v[tid] = c1b[h * 1024 + t0 + tid];
  }
  float Lprev = (c > 0) ? Lcum[h * 1024 + t0 - 1] : 0.f;
  int wave = tid >> 6, lane = tid & 63, quad = lane >> 4, r16 = lane & 15;
  int wm = (wave >> 1) * 64, wn = (wave & 1) * 64;

  // Phase 1: S = C @ Bᵀ (contraction over n=128), fragments straight from global
  f4 acc[4][4];
  #pragma unroll
  for (int i = 0; i < 4; i++)
    #pragma unroll
    for (int j = 0; j < 4; j++) acc[i][j] = (f4){0.f, 0.f, 0.f, 0.f};
  #pragma unroll
  for (int kk = 0; kk < 4; ++kk){
    short8 af[4], bf[4];
    #pragma unroll
    for (int i = 0; i < 4; i++)
      af[i] = *(const short8*)(Cb + (size_t)(t0 + wm + i * 16 + r16) * 4096 + h * 128 + kk * 32 + quad * 8);
    #pragma unroll
    for (int j = 0; j < 4; j++)
      bf[j] = *(const short8*)(Bbg + (size_t)(t0 + wn + j * 16 + r16) * 4096 + h * 128 + kk * 32 + quad * 8);
    #pragma unroll
    for (int i = 0; i < 4; i++)
      #pragma unroll
      for (int j = 0; j < 4; j++)
        acc[i][j] = __builtin_amdgcn_mfma_f32_16x16x32_bf16(af[i], bf[j], acc[i][j], 0, 0, 0);
  }
  __syncthreads();   // Lc/u2v/c1v visible

  // Phase 2: weight + mask, pack G to LDS (bf16)
  #pragma unroll
  for (int i = 0; i < 4; i++){
    #pragma unroll
    for (int rr = 0; rr < 4; ++rr){
      int trow = wm + i * 16 + quad * 4 + rr;
      float Lt = Lc[trow];
      #pragma unroll
      for (int j = 0; j < 4; j++){
        int scol = wn + j * 16 + r16;
        float g = 0.f;
        if (scol <= trow){
          float wcoef = (scol == trow) ? c1v[scol] : u2v[scol];
          g = acc[i][j][rr] * wcoef * __expf(Lt - Lc[scol]);
        }
        Gt[trow * GS + scol] = f2b(g);
      }
    }
  }
  __syncthreads();

  // Phase 3: Y1 = G @ X (K=s), Y2 = C @ H̃ᵀ (K=n); wave covers 32 t-rows x 64 p-cols
  f4 accY[2][4], accZ[2][4];
  #pragma unroll
  for (int i = 0; i < 2; i++)
    #pragma unroll
    for (int j = 0; j < 4; j++){ accY[i][j] = (f4){0.f,0.f,0.f,0.f}; accZ[i][j] = (f4){0.f,0.f,0.f,0.f}; }
  int m0 = wave * 32;
  #pragma unroll
  for (int kk = 0; kk < 4; ++kk){
    short8 ag[2], ac[2], bx[4], bh[4];
    #pragma unroll
    for (int i = 0; i < 2; i++){
      ag[i] = *(const short8*)&Gt[(m0 + i * 16 + r16) * GS + kk * 32 + quad * 8];
      ac[i] = *(const short8*)(Cb + (size_t)(t0 + m0 + i * 16 + r16) * 4096 + h * 128 + kk * 32 + quad * 8);
    }
    #pragma unroll
    for (int j = 0; j < 4; j++){
      bx[j] = *(const short8*)(xTb + (size_t)(h * 64 + j * 16 + r16) * 1024 + t0 + kk * 32 + quad * 8);
      bh[j] = *(const short8*)(Hused + ((size_t)(h * 8 + c) * 64 + j * 16 + r16) * 128 + kk * 32 + quad * 8);
    }
    #pragma unroll
    for (int i = 0; i < 2; i++)
      #pragma unroll
      for (int j = 0; j < 4; j++){
        accY[i][j] = __builtin_amdgcn_mfma_f32_16x16x32_bf16(ag[i], bx[j], accY[i][j], 0, 0, 0);
        accZ[i][j] = __builtin_amdgcn_mfma_f32_16x16x32_bf16(ac[i], bh[j], accZ[i][j], 0, 0, 0);
      }
  }
  #pragma unroll
  for (int i = 0; i < 2; i++)
    #pragma unroll
    for (int rr = 0; rr < 4; ++rr){
      int trow = m0 + i * 16 + quad * 4 + rr;
      float ei = __expf(Lc[trow] - Lprev);
      #pragma unroll
      for (int j = 0; j < 4; j++){
        int p = j * 16 + r16;
        ybuf[(size_t)(t0 + trow) * 2048 + h * 64 + p] = accY[i][j][rr] + ei * accZ[i][j][rr];
      }
    }
}

// ---- y = (y + D*x) * silu(z), cast bf16 ----
__global__ __launch_bounds__(256) void post_kernel(const float* __restrict__ y, const float* __restrict__ proj,
                                                   const float* __restrict__ D_par, short* __restrict__ yb){
  int i = (blockIdx.x * 256 + threadIdx.x) * 4;
  int t = i >> 11, d = i & 2047;
  int h = d >> 6;
  f4 yv = *(const f4*)(y + i);
  f4 xv = *(const f4*)(proj + (size_t)t * DPROJ + 2048 + d);
  f4 zv = *(const f4*)(proj + (size_t)t * DPROJ + d);
  float Dp = D_par[h];
  float o0 = (yv.x + Dp * xv.x) * (zv.x / (1.f + __expf(-zv.x)));
  float o1 = (yv.y + Dp * xv.y) * (zv.y / (1.f + __expf(-zv.y)));
  float o2 = (yv.z + Dp * xv.z) * (zv.z / (1.f + __expf(-zv.z)));
  float o3 = (yv.w + Dp * xv.w) * (zv.w / (1.f + __expf(-zv.w)));
  uint32_t lo = (uint32_t)(uint16_t)f2b(o0) | ((uint32_t)(uint16_t)f2b(o1) << 16);
  uint32_t hi = (uint32_t)(uint16_t)f2b(o2) | ((uint32_t)(uint16_t)f2b(o3) << 16);
  uint2 pk; pk.x = lo; pk.y = hi;
  *(uint2*)(yb + i) = pk;
}

extern "C" void kernel_launch(void* const* d_in, const int* in_sizes, int n_in,
                              void* d_out, int out_size, void* d_ws, size_t ws_size,
                              hipStream_t stream){
  const float* u       = (const float*)d_in[0];
  const float* W_in    = (const float*)d_in[1];
  const float* dt_bias = (const float*)d_in[2];
  const float* B_bias  = (const float*)d_in[3];
  const float* C_bias  = (const float*)d_in[4];
  const float* Bn_w    = (const float*)d_in[5];
  const float* Cn_w    = (const float*)d_in[6];
  const float* D_par   = (const float*)d_in[7];
  const float* W_out   = (const float*)d_in[8];
  float* out = (float*)d_out;

  char* ws = (char*)d_ws;
  short* u16   = (short*)(ws + 0);          //  2,097,152
  short* WtIn  = (short*)(ws + 2097152);    //  9,175,040  [4480][1024] bf16
  short* WtOut = (short*)(ws + 11272192);   //  4,194,304  [1024][2048] bf16
  float* proj  = (float*)(ws + 15466496);   // 18,350,080  [1024][4480] fp32
  f4*    coefA = (f4*)   (ws + 33816576);   //    524,288  [1024*32] {la,c1,c2n,dt}
  float* cosb  = (float*)(ws + 34340864);   //  4,194,304  [1024][1024]
  float* sinb  = (float*)(ws + 38535168);   //  4,194,304
  short* Bb    = (short*)(ws + 42729472);   //  8,388,608  [1024][4096] bf16
  short* Cb    = (short*)(ws + 51118080);   //  8,388,608
  short* xTb   = (short*)(ws + 59506688);   //  4,194,304  [2048][1024] bf16
  float* Lcum  = (float*)(ws + 63700992);   //    131,072  [32][1024]
  float* u2b   = (float*)(ws + 63832064);   //    131,072
  float* c1b   = (float*)(ws + 63963136);   //    131,072
  short* Hpart = (short*)(ws + 64094208);   //  4,194,304  [32][8][64][128] bf16
  short* Hused = (short*)(ws + 68288512);   //  4,194,304
  float* ybuf  = (float*)(ws + 72482816);   //  8,388,608  [1024][2048]
  short* yb16  = (short*)(ws + 80871424);   //  4,194,304  -> total 85,065,728 B

  cast_kernel<<<1024, 256, 0, stream>>>(u, u16);
  transpose_cast<<<dim3(140, 32), dim3(32, 8), 0, stream>>>(W_in, WtIn, 1024, 4480, 4480, 0);
  transpose_cast<<<dim3(32, 64), dim3(32, 8), 0, stream>>>(W_out, WtOut, 2048, 1024, 1024, 0);
  gemm_bt<<<dim3(35, 8), 256, 0, stream>>>(u16, WtIn, proj, 1024, 4480, 1024);
  prep_kernel<<<128, 256, 0, stream>>>(proj, dt_bias, coefA);
  scanL_kernel<<<32, 256, 0, stream>>>(coefA, Lcum, u2b, c1b);
  theta2_kernel<<<1024, 256, 0, stream>>>(proj, coefA, cosb, sinb);
  bc_kernel<<<1024, 256, 0, stream>>>(proj, B_bias, C_bias, Bn_w, Cn_w, cosb, sinb, Bb, Cb);
  transpose_cast<<<dim3(64, 32), dim3(32, 8), 0, stream>>>(proj, xTb, 1024, 2048, 4480, 2048);
  hpart_kernel<<<256, 256, 0, stream>>>(xTb, Bb, Lcum, u2b, Hpart);
  hscan_kernel<<<1024, 256, 0, stream>>>(Hpart, Lcum, Hused);
  chunky_kernel<<<256, 256, 0, stream>>>(Cb, Bb, xTb, Hused, Lcum, u2b, c1b, ybuf);
  post_kernel<<<2048, 256, 0, stream>>>(ybuf, proj, D_par, yb16);
  gemm_bt<<<dim3(8, 8), 256, 0, stream>>>(yb16, WtOut, out, 1024, 1024, 2048);
}

// Round 4
// 238.666 us; speedup vs baseline: 3.7908x; 1.1184x over previous
//
#include <hip/hip_runtime.h>
#include <stdint.h>

#define SEQ     1024
#define DPROJ   4480
// proj columns: z=0, x=2048, Bp=4096, Cp=4224, dd_dt=4352, dd_A=4384, trap=4416, ang=4448

typedef __attribute__((ext_vector_type(8))) short short8;
typedef __attribute__((ext_vector_type(4))) float f4;

__device__ __forceinline__ short f2b(float f){
  union { float f; uint32_t u; } v; v.f = f;
  uint32_t r = (v.u + 0x7fffu + ((v.u >> 16) & 1u)) >> 16;
  return (short)(uint16_t)r;
}
__device__ __forceinline__ float b2f(uint16_t u){
  union { uint32_t u; float f; } v; v.u = ((uint32_t)u) << 16; return v.f;
}
__device__ __forceinline__ uint32_t pack2(float lo, float hi){
  return (uint32_t)(uint16_t)f2b(lo) | ((uint32_t)(uint16_t)f2b(hi) << 16);
}
__device__ __forceinline__ float softplus_f(float x){
  return x > 20.f ? x : log1pf(__expf(x));
}
// async global->LDS 16B/lane; lptr must be wave-uniform-base + lane*16 order
__device__ __forceinline__ void gload_lds16(const short* g, short* l){
  __builtin_amdgcn_global_load_lds((const __attribute__((address_space(1))) void*)g,
                                   (__attribute__((address_space(3))) void*)l, 16, 0, 0);
}

// ---- cast fp32 -> bf16 ----
__global__ __launch_bounds__(256) void cast_kernel(const float* __restrict__ in, short* __restrict__ out){
  int i = (blockIdx.x * 256 + threadIdx.x) * 4;
  f4 v = *(const f4*)(in + i);
  uint2 pk; pk.x = pack2(v.x, v.y); pk.y = pack2(v.z, v.w);
  *(uint2*)(out + i) = pk;
}

// ---- transpose + cast: out[c][R] = in[r][lda] window (c0..c0+C). grid(C/32, R/32), block(32,8) ----
__global__ __launch_bounds__(256) void transpose_cast(const float* __restrict__ in, short* __restrict__ out,
                                                      int R, int C, int lda, int c0){
  __shared__ float tile[32][33];
  int bc = blockIdx.x * 32;
  int br = blockIdx.y * 32;
  int tx = threadIdx.x, ty = threadIdx.y;
  #pragma unroll
  for (int i = 0; i < 32; i += 8)
    tile[ty + i][tx] = in[(size_t)(br + ty + i) * lda + c0 + bc + tx];
  __syncthreads();
  #pragma unroll
  for (int i = 0; i < 32; i += 8)
    out[(size_t)(bc + ty + i) * R + br + tx] = f2b(tile[tx][ty + i]);
}

// ---- bf16 MFMA GEMM (m97-style async staging): C[z][M][N] += A[M][k0:k0+klen] @ Bt[N][k0:k0+klen]ᵀ
// grid (N/128, M/128, splits); k0 = blockIdx.z * klen
__global__ __launch_bounds__(256) void gemm_bt(const short* __restrict__ A, const short* __restrict__ Bt,
                                               float* __restrict__ C, int M, int N, int K, int klen){
  __shared__ __align__(16) short As[128 * 32];
  __shared__ __align__(16) short Bs[128 * 32];
  const int tid  = threadIdx.x;
  const int wave = tid >> 6;
  const int lane = tid & 63;
  const int m0 = blockIdx.y * 128;
  const int n0 = blockIdx.x * 128;
  const int k0 = blockIdx.z * klen;
  C += (size_t)blockIdx.z * M * N;
  const int wm = (wave >> 1) * 64;
  const int wn = (wave & 1) * 64;
  const int quad = lane >> 4;
  const int r16  = lane & 15;

  f4 acc[4][4];
  #pragma unroll
  for (int i = 0; i < 4; i++)
    #pragma unroll
    for (int j = 0; j < 4; j++) acc[i][j] = (f4){0.f, 0.f, 0.f, 0.f};

  // staging: slot tid (+256): row = tid>>2 (0..63 / 64..127), kq = tid&3 -> 16B
  const int row0 = tid >> 2;
  const int kq   = tid & 3;
  const short* gA0 = A  + (size_t)(m0 + row0) * K + k0 + kq * 8;
  const short* gA1 = A  + (size_t)(m0 + row0 + 64) * K + k0 + kq * 8;
  const short* gB0 = Bt + (size_t)(n0 + row0) * K + k0 + kq * 8;
  const short* gB1 = Bt + (size_t)(n0 + row0 + 64) * K + k0 + kq * 8;
  short* lA0 = &As[(size_t)tid * 8];
  short* lA1 = &As[(size_t)(tid + 256) * 8];
  short* lB0 = &Bs[(size_t)tid * 8];
  short* lB1 = &Bs[(size_t)(tid + 256) * 8];

  const int nk = klen >> 5;
  for (int kt = 0; kt < nk; ++kt){
    const int ko = kt * 32;
    __syncthreads();           // previous iter's ds_reads done before overwrite
    gload_lds16(gA0 + ko, lA0);
    gload_lds16(gA1 + ko, lA1);
    gload_lds16(gB0 + ko, lB0);
    gload_lds16(gB1 + ko, lB1);
    __syncthreads();           // drains vmcnt -> tile visible
    short8 af[4], bf[4];
    #pragma unroll
    for (int i = 0; i < 4; i++){
      af[i] = *(const short8*)&As[(wm + i * 16 + r16) * 32 + quad * 8];
      bf[i] = *(const short8*)&Bs[(wn + i * 16 + r16) * 32 + quad * 8];
    }
    #pragma unroll
    for (int i = 0; i < 4; i++)
      #pragma unroll
      for (int j = 0; j < 4; j++)
        acc[i][j] = __builtin_amdgcn_mfma_f32_16x16x32_bf16(af[i], bf[j], acc[i][j], 0, 0, 0);
  }

  #pragma unroll
  for (int i = 0; i < 4; i++)
    #pragma unroll
    for (int j = 0; j < 4; j++)
      #pragma unroll
      for (int rr = 0; rr < 4; ++rr){
        int row = m0 + wm + i * 16 + quad * 4 + rr;
        int col = n0 + wn + j * 16 + r16;
        C[(size_t)row * N + col] = acc[i][j][rr];
      }
}

// ---- sum 4 split-K partials (each 1M fp32) -> out ----
__global__ __launch_bounds__(256) void reduce4_kernel(const float* __restrict__ p, float* __restrict__ out){
  int i = (blockIdx.x * 256 + threadIdx.x) * 4;
  f4 a = *(const f4*)(p + i);
  f4 b = *(const f4*)(p + 1048576 + i);
  f4 c = *(const f4*)(p + 2097152 + i);
  f4 d = *(const f4*)(p + 3145728 + i);
  f4 s; s.x = (a.x + b.x) + (c.x + d.x); s.y = (a.y + b.y) + (c.y + d.y);
  s.z = (a.z + b.z) + (c.z + d.z); s.w = (a.w + b.w) + (c.w + d.w);
  *(f4*)(out + i) = s;
}

// ---- per-(t,h): coefA[t*32+h] = {la=log a, c1=dt*lam, c2n=dt*(1-lam), dt} ----
__global__ __launch_bounds__(256) void prep_kernel(const float* __restrict__ proj,
                                                   const float* __restrict__ dt_bias,
                                                   f4* __restrict__ coefA){
  int idx = blockIdx.x * 256 + threadIdx.x;
  int t = idx >> 5, h = idx & 31;
  const float* row = proj + (size_t)t * DPROJ;
  float dt  = softplus_f(row[4352 + h] + dt_bias[h]);
  float Ah  = -fmaxf(softplus_f(row[4384 + h]), 1e-4f);
  float lam = 1.f / (1.f + __expf(-row[4416 + h]));
  f4 c; c.x = Ah * dt; c.y = dt * lam; c.z = dt * (1.f - lam); c.w = dt;
  coefA[idx] = c;
}

// ---- per-head parallel prefix scan: Lcum[h][t] = cumsum(la); u2 = c1 + c2n[t+1]; c1 copy ----
__global__ __launch_bounds__(256) void scanL_kernel(const f4* __restrict__ coefA,
                                                    float* __restrict__ Lcum,
                                                    float* __restrict__ u2b,
                                                    float* __restrict__ c1b){
  int h = blockIdx.x;
  int tid = threadIdx.x;
  int t0 = tid * 4;
  float v[4], c1[4], c2n[4];
  #pragma unroll
  for (int i = 0; i < 4; i++){
    f4 cc = coefA[(t0 + i) * 32 + h];
    v[i] = cc.x; c1[i] = cc.y;
  }
  #pragma unroll
  for (int i = 0; i < 4; i++){
    int t = t0 + i;
    c2n[i] = (t < 1023) ? coefA[(t + 1) * 32 + h].z : 0.f;
  }
  v[1] += v[0]; v[2] += v[1]; v[3] += v[2];
  float tot = v[3], sc = tot;
  int lane = tid & 63, wave = tid >> 6;
  #pragma unroll
  for (int off = 1; off < 64; off <<= 1){
    float n = __shfl_up(sc, off, 64);
    if (lane >= off) sc += n;
  }
  __shared__ float wsum[4];
  if (lane == 63) wsum[wave] = sc;
  __syncthreads();
  float base = sc - tot;
  for (int w = 0; w < wave; ++w) base += wsum[w];
  #pragma unroll
  for (int i = 0; i < 4; i++){
    int t = t0 + i;
    Lcum[h * 1024 + t] = base + v[i];
    u2b[h * 1024 + t]  = c1[i] + c2n[i];
    c1b[h * 1024 + t]  = c1[i];
  }
}

// ---- theta cumsum via parallel scan: 1024 blocks = (h,k) ----
__global__ __launch_bounds__(256) void theta2_kernel(const float* __restrict__ proj,
                                                     const f4* __restrict__ coefA,
                                                     float* __restrict__ cosb, float* __restrict__ sinb){
  int h = blockIdx.x >> 5, k = blockIdx.x & 31;
  int tid = threadIdx.x;
  int t0 = tid * 4;
  float v[4];
  #pragma unroll
  for (int i = 0; i < 4; i++){
    int t = t0 + i;
    v[i] = proj[(size_t)t * DPROJ + 4448 + k] * coefA[t * 32 + h].w;
  }
  v[1] += v[0]; v[2] += v[1]; v[3] += v[2];
  float tot = v[3], sc = tot;
  int lane = tid & 63, wave = tid >> 6;
  #pragma unroll
  for (int off = 1; off < 64; off <<= 1){
    float n = __shfl_up(sc, off, 64);
    if (lane >= off) sc += n;
  }
  __shared__ float wsum[4];
  if (lane == 63) wsum[wave] = sc;
  __syncthreads();
  float base = sc - tot;
  for (int w = 0; w < wave; ++w) base += wsum[w];
  #pragma unroll
  for (int i = 0; i < 4; i++){
    float th = base + v[i];
    float s, c;
    __sincosf(th, &s, &c);
    int t = t0 + i;
    cosb[(size_t)t * 1024 + h * 32 + k] = c;
    sinb[(size_t)t * 1024 + h * 32 + k] = s;
  }
}

// ---- rmsnorm + bias + rope -> Bb/Cb bf16 [t][h*128+n] ----
__global__ __launch_bounds__(256) void bc_kernel(const float* __restrict__ proj,
                                                 const float* __restrict__ B_bias, const float* __restrict__ C_bias,
                                                 const float* __restrict__ Bn_w, const float* __restrict__ Cn_w,
                                                 const float* __restrict__ cosb, const float* __restrict__ sinb,
                                                 short* __restrict__ Bb, short* __restrict__ Cb){
  int t = blockIdx.x;
  int tid = threadIdx.x;
  __shared__ float vB[128], vC[128];
  __shared__ float red[4];
  int n = tid & 127;
  bool isC = tid >= 128;
  float val = proj[(size_t)t * DPROJ + 4096 + (isC ? 128 : 0) + n];
  float ss = val * val;
  #pragma unroll
  for (int off = 32; off >= 1; off >>= 1) ss += __shfl_down(ss, off);
  int wave = tid >> 6, lane = tid & 63;
  if (lane == 0) red[wave] = ss;
  __syncthreads();
  float rsv = isC ? rsqrtf((red[2] + red[3]) * (1.f / 128.f) + 1e-5f)
                  : rsqrtf((red[0] + red[1]) * (1.f / 128.f) + 1e-5f);
  float nv = val * rsv * (isC ? Cn_w[n] : Bn_w[n]);
  (isC ? vC : vB)[n] = nv;
  __syncthreads();
  const float* bias = isC ? C_bias : B_bias;
  const float* base = isC ? vC : vB;
  short* outp = isC ? Cb : Bb;
  const float* cb = cosb + (size_t)t * 1024;
  const float* sb = sinb + (size_t)t * 1024;
  for (int h = 0; h < 32; ++h){
    float v = base[n] + bias[h * 128 + n];
    float o;
    if (n < 32){
      float v2 = base[n + 32] + bias[h * 128 + n + 32];
      float c = cb[h * 32 + n], s = sb[h * 32 + n];
      o = v * c - v2 * s;
    } else if (n < 64){
      int k = n - 32;
      float v1 = base[k] + bias[h * 128 + k];
      float c = cb[h * 32 + k], s = sb[h * 32 + k];
      o = v1 * s + v * c;
    } else {
      o = v;
    }
    outp[(size_t)t * 4096 + h * 128 + n] = f2b(o);
  }
}

// ---- per-chunk state contribution, MFMA form (verified R3) ----
__global__ __launch_bounds__(256) void hpart_kernel(const short* __restrict__ xTb, const short* __restrict__ Bb,
                                                    const float* __restrict__ Lcum, const float* __restrict__ u2b,
                                                    short* __restrict__ Hpart){
  int h = blockIdx.x >> 3, c = blockIdx.x & 7;
  int t0 = c * 128;
  int tid = threadIdx.x;
  __shared__ float wS[128];
  if (tid < 128){
    float Lend = Lcum[h * 1024 + t0 + 127];
    wS[tid] = __expf(Lend - Lcum[h * 1024 + t0 + tid]) * u2b[h * 1024 + t0 + tid];
  }
  __syncthreads();
  int wave = tid >> 6, lane = tid & 63, quad = lane >> 4, r16 = lane & 15;
  int n0 = wave * 32;
  f4 acc[4][2];
  #pragma unroll
  for (int i = 0; i < 4; i++)
    #pragma unroll
    for (int j = 0; j < 2; j++) acc[i][j] = (f4){0.f, 0.f, 0.f, 0.f};

  const ushort* Bh = (const ushort*)Bb + (size_t)t0 * 4096 + h * 128;
  #pragma unroll
  for (int kk = 0; kk < 4; ++kk){
    int sb = kk * 32 + quad * 8;
    short8 af[4];
    #pragma unroll
    for (int i = 0; i < 4; i++){
      int p = i * 16 + r16;
      af[i] = *(const short8*)(xTb + (size_t)(h * 64 + p) * 1024 + t0 + sb);
    }
    float wv[8];
    #pragma unroll
    for (int jj = 0; jj < 8; jj++) wv[jj] = wS[sb + jj];
    short8 bfr[2];
    #pragma unroll
    for (int j = 0; j < 2; j++){
      int n = n0 + j * 16 + r16;
      float e[8];
      #pragma unroll
      for (int jj = 0; jj < 8; jj++)
        e[jj] = b2f(Bh[(size_t)(sb + jj) * 4096 + n]) * wv[jj];
      union { short8 s; uint32_t u[4]; } fr;
      #pragma unroll
      for (int q = 0; q < 4; q++) fr.u[q] = pack2(e[2 * q], e[2 * q + 1]);
      bfr[j] = fr.s;
    }
    #pragma unroll
    for (int i = 0; i < 4; i++)
      #pragma unroll
      for (int j = 0; j < 2; j++)
        acc[i][j] = __builtin_amdgcn_mfma_f32_16x16x32_bf16(af[i], bfr[j], acc[i][j], 0, 0, 0);
  }

  short* out = Hpart + ((size_t)(h * 8 + c)) * 8192;
  #pragma unroll
  for (int i = 0; i < 4; i++)
    #pragma unroll
    for (int rr = 0; rr < 4; ++rr){
      int p = i * 16 + quad * 4 + rr;
      #pragma unroll
      for (int j = 0; j < 2; j++){
        int n = n0 + j * 16 + r16;
        out[p * 128 + n] = f2b(acc[i][j][rr]);
      }
    }
}

// ---- 8-step state prefix: Hused[h][c] = H̃_{c-1} (bf16) ----
__global__ __launch_bounds__(256) void hscan_kernel(const short* __restrict__ Hpart,
                                                    const float* __restrict__ Lcum,
                                                    short* __restrict__ Hused){
  int idx = blockIdx.x * 256 + threadIdx.x;
  int h = idx >> 13, rem = idx & 8191;
  float acc = 0.f;
  float Lprev = 0.f;
  #pragma unroll
  for (int c = 0; c < 8; c++){
    Hused[((size_t)(h * 8 + c)) * 8192 + rem] = f2b(acc);
    float Lend = Lcum[h * 1024 + c * 128 + 127];
    float dec = __expf(Lend - Lprev);
    acc = dec * acc + b2f((uint16_t)Hpart[((size_t)(h * 8 + c)) * 8192 + rem]);
    Lprev = Lend;
  }
}

// ---- chunked dual form: per (h,c): S=C@Bᵀ -> weight -> Y = G@X + diag(einter)·(C@H̃ᵀ) ----
#define GS 144
__global__ __launch_bounds__(256) void chunky_kernel(const short* __restrict__ Cb, const short* __restrict__ Bbg,
                                                     const short* __restrict__ xTb, const short* __restrict__ Hused,
                                                     const float* __restrict__ Lcum, const float* __restrict__ u2b,
                                                     const float* __restrict__ c1b,
                                                     float* __restrict__ ybuf){
  int h = blockIdx.x >> 3, c = blockIdx.x & 7;
  int t0 = c * 128;
  __shared__ __align__(16) short Gt[128 * GS];
  __shared__ float Lc[128], u2v[128], c1v[128];
  int tid = threadIdx.x;
  if (tid < 128){
    Lc[tid]  = Lcum[h * 1024 + t0 + tid];
    u2v[tid] = u2b[h * 1024 + t0 + tid];
    c1v[tid] = c1b[h * 1024 + t0 + tid];
  }
  float Lprev = (c > 0) ? Lcum[h * 1024 + t0 - 1] : 0.f;
  int wave = tid >> 6, lane = tid & 63, quad = lane >> 4, r16 = lane & 15;
  int wm = (wave >> 1) * 64, wn = (wave & 1) * 64;

  f4 acc[4][4];
  #pragma unroll
  for (int i = 0; i < 4; i++)
    #pragma unroll
    for (int j = 0; j < 4; j++) acc[i][j] = (f4){0.f, 0.f, 0.f, 0.f};
  #pragma unroll
  for (int kk = 0; kk < 4; ++kk){
    short8 af[4], bf[4];
    #pragma unroll
    for (int i = 0; i < 4; i++)
      af[i] = *(const short8*)(Cb + (size_t)(t0 + wm + i * 16 + r16) * 4096 + h * 128 + kk * 32 + quad * 8);
    #pragma unroll
    for (int j = 0; j < 4; j++)
      bf[j] = *(const short8*)(Bbg + (size_t)(t0 + wn + j * 16 + r16) * 4096 + h * 128 + kk * 32 + quad * 8);
    #pragma unroll
    for (int i = 0; i < 4; i++)
      #pragma unroll
      for (int j = 0; j < 4; j++)
        acc[i][j] = __builtin_amdgcn_mfma_f32_16x16x32_bf16(af[i], bf[j], acc[i][j], 0, 0, 0);
  }
  __syncthreads();

  #pragma unroll
  for (int i = 0; i < 4; i++){
    #pragma unroll
    for (int rr = 0; rr < 4; ++rr){
      int trow = wm + i * 16 + quad * 4 + rr;
      float Lt = Lc[trow];
      #pragma unroll
      for (int j = 0; j < 4; j++){
        int scol = wn + j * 16 + r16;
        float g = 0.f;
        if (scol <= trow){
          float wcoef = (scol == trow) ? c1v[scol] : u2v[scol];
          g = acc[i][j][rr] * wcoef * __expf(Lt - Lc[scol]);
        }
        Gt[trow * GS + scol] = f2b(g);
      }
    }
  }
  __syncthreads();

  f4 accY[2][4], accZ[2][4];
  #pragma unroll
  for (int i = 0; i < 2; i++)
    #pragma unroll
    for (int j = 0; j < 4; j++){ accY[i][j] = (f4){0.f,0.f,0.f,0.f}; accZ[i][j] = (f4){0.f,0.f,0.f,0.f}; }
  int m0 = wave * 32;
  #pragma unroll
  for (int kk = 0; kk < 4; ++kk){
    short8 ag[2], ac[2], bx[4], bh[4];
    #pragma unroll
    for (int i = 0; i < 2; i++){
      ag[i] = *(const short8*)&Gt[(m0 + i * 16 + r16) * GS + kk * 32 + quad * 8];
      ac[i] = *(const short8*)(Cb + (size_t)(t0 + m0 + i * 16 + r16) * 4096 + h * 128 + kk * 32 + quad * 8);
    }
    #pragma unroll
    for (int j = 0; j < 4; j++){
      bx[j] = *(const short8*)(xTb + (size_t)(h * 64 + j * 16 + r16) * 1024 + t0 + kk * 32 + quad * 8);
      bh[j] = *(const short8*)(Hused + ((size_t)(h * 8 + c) * 64 + j * 16 + r16) * 128 + kk * 32 + quad * 8);
    }
    #pragma unroll
    for (int i = 0; i < 2; i++)
      #pragma unroll
      for (int j = 0; j < 4; j++){
        accY[i][j] = __builtin_amdgcn_mfma_f32_16x16x32_bf16(ag[i], bx[j], accY[i][j], 0, 0, 0);
        accZ[i][j] = __builtin_amdgcn_mfma_f32_16x16x32_bf16(ac[i], bh[j], accZ[i][j], 0, 0, 0);
      }
  }
  #pragma unroll
  for (int i = 0; i < 2; i++)
    #pragma unroll
    for (int rr = 0; rr < 4; ++rr){
      int trow = m0 + i * 16 + quad * 4 + rr;
      float ei = __expf(Lc[trow] - Lprev);
      #pragma unroll
      for (int j = 0; j < 4; j++){
        int p = j * 16 + r16;
        ybuf[(size_t)(t0 + trow) * 2048 + h * 64 + p] = accY[i][j][rr] + ei * accZ[i][j][rr];
      }
    }
}

// ---- y = (y + D*x) * silu(z), cast bf16 ----
__global__ __launch_bounds__(256) void post_kernel(const float* __restrict__ y, const float* __restrict__ proj,
                                                   const float* __restrict__ D_par, short* __restrict__ yb){
  int i = (blockIdx.x * 256 + threadIdx.x) * 4;
  int t = i >> 11, d = i & 2047;
  int h = d >> 6;
  f4 yv = *(const f4*)(y + i);
  f4 xv = *(const f4*)(proj + (size_t)t * DPROJ + 2048 + d);
  f4 zv = *(const f4*)(proj + (size_t)t * DPROJ + d);
  float Dp = D_par[h];
  float o0 = (yv.x + Dp * xv.x) * (zv.x / (1.f + __expf(-zv.x)));
  float o1 = (yv.y + Dp * xv.y) * (zv.y / (1.f + __expf(-zv.y)));
  float o2 = (yv.z + Dp * xv.z) * (zv.z / (1.f + __expf(-zv.z)));
  float o3 = (yv.w + Dp * xv.w) * (zv.w / (1.f + __expf(-zv.w)));
  uint2 pk; pk.x = pack2(o0, o1); pk.y = pack2(o2, o3);
  *(uint2*)(yb + i) = pk;
}

extern "C" void kernel_launch(void* const* d_in, const int* in_sizes, int n_in,
                              void* d_out, int out_size, void* d_ws, size_t ws_size,
                              hipStream_t stream){
  const float* u       = (const float*)d_in[0];
  const float* W_in    = (const float*)d_in[1];
  const float* dt_bias = (const float*)d_in[2];
  const float* B_bias  = (const float*)d_in[3];
  const float* C_bias  = (const float*)d_in[4];
  const float* Bn_w    = (const float*)d_in[5];
  const float* Cn_w    = (const float*)d_in[6];
  const float* D_par   = (const float*)d_in[7];
  const float* W_out   = (const float*)d_in[8];
  float* out = (float*)d_out;

  char* ws = (char*)d_ws;
  short* u16   = (short*)(ws + 0);          //  2,097,152
  short* WtIn  = (short*)(ws + 2097152);    //  9,175,040  [4480][1024] bf16
  short* WtOut = (short*)(ws + 11272192);   //  4,194,304  [1024][2048] bf16
  float* proj  = (float*)(ws + 15466496);   // 18,350,080  [1024][4480] fp32
  f4*    coefA = (f4*)   (ws + 33816576);   //    524,288  [1024*32] {la,c1,c2n,dt}
  float* cosb  = (float*)(ws + 34340864);   //  4,194,304  [1024][1024]
  float* sinb  = (float*)(ws + 38535168);   //  4,194,304
  short* Bb    = (short*)(ws + 42729472);   //  8,388,608  [1024][4096] bf16
  short* Cb    = (short*)(ws + 51118080);   //  8,388,608
  short* xTb   = (short*)(ws + 59506688);   //  4,194,304  [2048][1024] bf16
  float* Lcum  = (float*)(ws + 63700992);   //    131,072  [32][1024]
  float* u2b   = (float*)(ws + 63832064);   //    131,072
  float* c1b   = (float*)(ws + 63963136);   //    131,072
  short* Hpart = (short*)(ws + 64094208);   //  4,194,304  [32][8][64][128] bf16
  short* Hused = (short*)(ws + 68288512);   //  4,194,304
  float* ybuf  = (float*)(ws + 72482816);   //  8,388,608  [1024][2048]
  short* yb16  = (short*)(ws + 80871424);   //  4,194,304  -> total 85,065,728 B
  // split-K partials (16 MB) overlay proj — proj's last reader is post_kernel,
  // which completes before the out-GEMM launches.
  float* part  = proj;

  cast_kernel<<<1024, 256, 0, stream>>>(u, u16);
  transpose_cast<<<dim3(140, 32), dim3(32, 8), 0, stream>>>(W_in, WtIn, 1024, 4480, 4480, 0);
  transpose_cast<<<dim3(32, 64), dim3(32, 8), 0, stream>>>(W_out, WtOut, 2048, 1024, 1024, 0);
  gemm_bt<<<dim3(35, 8, 1), 256, 0, stream>>>(u16, WtIn, proj, 1024, 4480, 1024, 1024);
  prep_kernel<<<128, 256, 0, stream>>>(proj, dt_bias, coefA);
  scanL_kernel<<<32, 256, 0, stream>>>(coefA, Lcum, u2b, c1b);
  theta2_kernel<<<1024, 256, 0, stream>>>(proj, coefA, cosb, sinb);
  bc_kernel<<<1024, 256, 0, stream>>>(proj, B_bias, C_bias, Bn_w, Cn_w, cosb, sinb, Bb, Cb);
  transpose_cast<<<dim3(64, 32), dim3(32, 8), 0, stream>>>(proj, xTb, 1024, 2048, 4480, 2048);
  hpart_kernel<<<256, 256, 0, stream>>>(xTb, Bb, Lcum, u2b, Hpart);
  hscan_kernel<<<1024, 256, 0, stream>>>(Hpart, Lcum, Hused);
  chunky_kernel<<<256, 256, 0, stream>>>(Cb, Bb, xTb, Hused, Lcum, u2b, c1b, ybuf);
  post_kernel<<<2048, 256, 0, stream>>>(ybuf, proj, D_par, yb16);
  gemm_bt<<<dim3(8, 8, 4), 256, 0, stream>>>(yb16, WtOut, part, 1024, 1024, 2048, 512);
  reduce4_kernel<<<1024, 256, 0, stream>>>(part, out);
}

// Round 5
// 218.876 us; speedup vs baseline: 4.1335x; 1.0904x over previous
//
#include <hip/hip_runtime.h>
#include <stdint.h>

#define SEQ     1024
#define DPROJ   4480
// proj columns: z=0, x=2048, Bp=4096, Cp=4224, dd_dt=4352, dd_A=4384, trap=4416, ang=4448

typedef __attribute__((ext_vector_type(8))) short short8;
typedef __attribute__((ext_vector_type(4))) float f4;

__device__ __forceinline__ short f2b(float f){
  union { float f; uint32_t u; } v; v.f = f;
  uint32_t r = (v.u + 0x7fffu + ((v.u >> 16) & 1u)) >> 16;
  return (short)(uint16_t)r;
}
__device__ __forceinline__ float b2f(uint16_t u){
  union { uint32_t u; float f; } v; v.u = ((uint32_t)u) << 16; return v.f;
}
__device__ __forceinline__ uint32_t pack2(float lo, float hi){
  return (uint32_t)(uint16_t)f2b(lo) | ((uint32_t)(uint16_t)f2b(hi) << 16);
}
__device__ __forceinline__ float softplus_f(float x){
  return x > 20.f ? x : log1pf(__expf(x));
}
// async global->LDS 16B/lane; lds dest must be wave-uniform base + lane*16 order
__device__ __forceinline__ void gload_lds16(const short* g, short* l){
  __builtin_amdgcn_global_load_lds((const __attribute__((address_space(1))) void*)g,
                                   (__attribute__((address_space(3))) void*)l, 16, 0, 0);
}

// ---- cast fp32 -> bf16 ----
__global__ __launch_bounds__(256) void cast_kernel(const float* __restrict__ in, short* __restrict__ out){
  int i = (blockIdx.x * 256 + threadIdx.x) * 4;
  f4 v = *(const f4*)(in + i);
  uint2 pk; pk.x = pack2(v.x, v.y); pk.y = pack2(v.z, v.w);
  *(uint2*)(out + i) = pk;
}

// ---- transpose + cast: out[c][R] = in[r][lda] window. grid(C/32, R/128), block 256.
// 128-row tiles; epilogue reads ds_read_b128, stores 8B packed (4 rows/lane).
__global__ __launch_bounds__(256) void transpose_cast(const float* __restrict__ in, short* __restrict__ out,
                                                      int R, int C, int lda, int c0){
  __shared__ float tile[32][132];   // [col][row]; 132*4B=528B row stride (16B-aligned)
  int bc = blockIdx.x * 32;
  int br = blockIdx.y * 128;
  int tid = threadIdx.x;
  int c = tid & 31, r0 = tid >> 5;
  #pragma unroll
  for (int i = 0; i < 16; i++){
    int r = r0 + i * 8;
    tile[c][r] = in[(size_t)(br + r) * lda + c0 + bc + c];
  }
  __syncthreads();
  #pragma unroll
  for (int i = 0; i < 4; i++){
    int task = tid + 256 * i;       // 0..1023
    int cc = task >> 5;             // 0..31
    int rg = (task & 31) * 4;       // 0..124
    f4 v = *(const f4*)&tile[cc][rg];
    uint2 pk; pk.x = pack2(v.x, v.y); pk.y = pack2(v.z, v.w);
    *(uint2*)(out + (size_t)(bc + cc) * R + br + rg) = pk;
  }
}

// ---- GEMM1: proj[1024][4480] = u16[1024][1024] @ WtIn[4480][1024]ᵀ
// 128x160 tile -> grid (28,8) = 224 blocks = single pass on 256 CUs.
__global__ __launch_bounds__(256) void gemm1_kernel(const short* __restrict__ A, const short* __restrict__ Bt,
                                                    float* __restrict__ C){
  const int M = 1024, N = 4480, K = 1024;
  __shared__ __align__(16) short As[128 * 32];
  __shared__ __align__(16) short Bs[160 * 32];
  const int tid  = threadIdx.x;
  const int wave = tid >> 6;
  const int lane = tid & 63;
  const int m0 = blockIdx.y * 128;
  const int n0 = blockIdx.x * 160;
  const int wm = (wave >> 1) * 64;
  const int wn = (wave & 1) * 80;
  const int quad = lane >> 4;
  const int r16  = lane & 15;

  f4 acc[4][5];
  #pragma unroll
  for (int i = 0; i < 4; i++)
    #pragma unroll
    for (int j = 0; j < 5; j++) acc[i][j] = (f4){0.f, 0.f, 0.f, 0.f};

  const int row0 = tid >> 2;
  const int kq   = tid & 3;
  const short* gA0 = A  + (size_t)(m0 + row0) * K + kq * 8;
  const short* gA1 = A  + (size_t)(m0 + row0 + 64) * K + kq * 8;
  const short* gB0 = Bt + (size_t)(n0 + row0) * K + kq * 8;
  const short* gB1 = Bt + (size_t)(n0 + row0 + 64) * K + kq * 8;
  const short* gB2 = Bt + (size_t)(n0 + row0 + 128) * K + kq * 8;   // used by tid<128
  short* lA0 = &As[(size_t)tid * 8];
  short* lA1 = &As[(size_t)(tid + 256) * 8];
  short* lB0 = &Bs[(size_t)tid * 8];
  short* lB1 = &Bs[(size_t)(tid + 256) * 8];
  short* lB2 = &Bs[(size_t)(tid + 512) * 8];

  for (int kt = 0; kt < 32; ++kt){
    const int ko = kt * 32;
    __syncthreads();
    gload_lds16(gA0 + ko, lA0);
    gload_lds16(gA1 + ko, lA1);
    gload_lds16(gB0 + ko, lB0);
    gload_lds16(gB1 + ko, lB1);
    if (tid < 128) gload_lds16(gB2 + ko, lB2);   // waves 0,1 fully active
    __syncthreads();
    short8 af[4], bf[5];
    #pragma unroll
    for (int i = 0; i < 4; i++)
      af[i] = *(const short8*)&As[(wm + i * 16 + r16) * 32 + quad * 8];
    #pragma unroll
    for (int j = 0; j < 5; j++)
      bf[j] = *(const short8*)&Bs[(wn + j * 16 + r16) * 32 + quad * 8];
    #pragma unroll
    for (int i = 0; i < 4; i++)
      #pragma unroll
      for (int j = 0; j < 5; j++)
        acc[i][j] = __builtin_amdgcn_mfma_f32_16x16x32_bf16(af[i], bf[j], acc[i][j], 0, 0, 0);
  }

  #pragma unroll
  for (int i = 0; i < 4; i++)
    #pragma unroll
    for (int j = 0; j < 5; j++)
      #pragma unroll
      for (int rr = 0; rr < 4; ++rr){
        int row = m0 + wm + i * 16 + quad * 4 + rr;
        int col = n0 + wn + j * 16 + r16;
        C[(size_t)row * N + col] = acc[i][j][rr];
      }
}

// ---- GEMM2: out[1024][1024] += yb16[1024][2048] @ WtOut[1024][2048]ᵀ, split-K=4, fp32 atomics.
__global__ __launch_bounds__(256) void gemm2_kernel(const short* __restrict__ A, const short* __restrict__ Bt,
                                                    float* __restrict__ C){
  const int N = 1024, K = 2048, klen = 512;
  __shared__ __align__(16) short As[128 * 32];
  __shared__ __align__(16) short Bs[128 * 32];
  const int tid  = threadIdx.x;
  const int wave = tid >> 6;
  const int lane = tid & 63;
  const int m0 = blockIdx.y * 128;
  const int n0 = blockIdx.x * 128;
  const int k0 = blockIdx.z * klen;
  const int wm = (wave >> 1) * 64;
  const int wn = (wave & 1) * 64;
  const int quad = lane >> 4;
  const int r16  = lane & 15;

  f4 acc[4][4];
  #pragma unroll
  for (int i = 0; i < 4; i++)
    #pragma unroll
    for (int j = 0; j < 4; j++) acc[i][j] = (f4){0.f, 0.f, 0.f, 0.f};

  const int row0 = tid >> 2;
  const int kq   = tid & 3;
  const short* gA0 = A  + (size_t)(m0 + row0) * K + k0 + kq * 8;
  const short* gA1 = A  + (size_t)(m0 + row0 + 64) * K + k0 + kq * 8;
  const short* gB0 = Bt + (size_t)(n0 + row0) * K + k0 + kq * 8;
  const short* gB1 = Bt + (size_t)(n0 + row0 + 64) * K + k0 + kq * 8;
  short* lA0 = &As[(size_t)tid * 8];
  short* lA1 = &As[(size_t)(tid + 256) * 8];
  short* lB0 = &Bs[(size_t)tid * 8];
  short* lB1 = &Bs[(size_t)(tid + 256) * 8];

  for (int kt = 0; kt < klen / 32; ++kt){
    const int ko = kt * 32;
    __syncthreads();
    gload_lds16(gA0 + ko, lA0);
    gload_lds16(gA1 + ko, lA1);
    gload_lds16(gB0 + ko, lB0);
    gload_lds16(gB1 + ko, lB1);
    __syncthreads();
    short8 af[4], bf[4];
    #pragma unroll
    for (int i = 0; i < 4; i++){
      af[i] = *(const short8*)&As[(wm + i * 16 + r16) * 32 + quad * 8];
      bf[i] = *(const short8*)&Bs[(wn + i * 16 + r16) * 32 + quad * 8];
    }
    #pragma unroll
    for (int i = 0; i < 4; i++)
      #pragma unroll
      for (int j = 0; j < 4; j++)
        acc[i][j] = __builtin_amdgcn_mfma_f32_16x16x32_bf16(af[i], bf[j], acc[i][j], 0, 0, 0);
  }

  #pragma unroll
  for (int i = 0; i < 4; i++)
    #pragma unroll
    for (int j = 0; j < 4; j++)
      #pragma unroll
      for (int rr = 0; rr < 4; ++rr){
        int row = m0 + wm + i * 16 + quad * 4 + rr;
        int col = n0 + wn + j * 16 + r16;
        unsafeAtomicAdd(&C[(size_t)row * N + col], acc[i][j][rr]);
      }
}

// ---- fused prep + per-head prefix scan: Lcum/u2b/c1b/dtb from proj directly ----
__global__ __launch_bounds__(256) void scanL_kernel(const float* __restrict__ proj,
                                                    const float* __restrict__ dt_bias,
                                                    float* __restrict__ Lcum, float* __restrict__ u2b,
                                                    float* __restrict__ c1b, float* __restrict__ dtb){
  int h = blockIdx.x;
  int tid = threadIdx.x;
  int t0 = tid * 4;
  float dtbias = dt_bias[h];
  float dt5[5], lam5[5];
  #pragma unroll
  for (int i = 0; i < 5; i++){
    int t = t0 + i;
    if (t < 1024){
      const float* row = proj + (size_t)t * DPROJ;
      dt5[i]  = softplus_f(row[4352 + h] + dtbias);
      lam5[i] = 1.f / (1.f + __expf(-row[4416 + h]));
    } else { dt5[i] = 0.f; lam5[i] = 0.f; }
  }
  float v[4], c1[4], c2n[4];
  #pragma unroll
  for (int i = 0; i < 4; i++){
    int t = t0 + i;
    const float* row = proj + (size_t)t * DPROJ;
    float Ah = -fmaxf(softplus_f(row[4384 + h]), 1e-4f);
    v[i]   = Ah * dt5[i];
    c1[i]  = dt5[i] * lam5[i];
    c2n[i] = dt5[i + 1] * (1.f - lam5[i + 1]);
  }
  v[1] += v[0]; v[2] += v[1]; v[3] += v[2];
  float tot = v[3], sc = tot;
  int lane = tid & 63, wave = tid >> 6;
  #pragma unroll
  for (int off = 1; off < 64; off <<= 1){
    float n = __shfl_up(sc, off, 64);
    if (lane >= off) sc += n;
  }
  __shared__ float wsum[4];
  if (lane == 63) wsum[wave] = sc;
  __syncthreads();
  float base = sc - tot;
  for (int w = 0; w < wave; ++w) base += wsum[w];
  #pragma unroll
  for (int i = 0; i < 4; i++){
    int t = t0 + i;
    Lcum[h * 1024 + t] = base + v[i];
    u2b[h * 1024 + t]  = c1[i] + c2n[i];
    c1b[h * 1024 + t]  = c1[i];
    dtb[h * 1024 + t]  = dt5[i];
  }
}

// ---- theta cumsum via parallel scan: 1024 blocks = (h,k) ----
__global__ __launch_bounds__(256) void theta2_kernel(const float* __restrict__ proj,
                                                     const float* __restrict__ dtb,
                                                     float* __restrict__ cosb, float* __restrict__ sinb){
  int h = blockIdx.x >> 5, k = blockIdx.x & 31;
  int tid = threadIdx.x;
  int t0 = tid * 4;
  f4 dtv = *(const f4*)&dtb[h * 1024 + t0];
  float v[4];
  #pragma unroll
  for (int i = 0; i < 4; i++)
    v[i] = proj[(size_t)(t0 + i) * DPROJ + 4448 + k] * dtv[i];
  v[1] += v[0]; v[2] += v[1]; v[3] += v[2];
  float tot = v[3], sc = tot;
  int lane = tid & 63, wave = tid >> 6;
  #pragma unroll
  for (int off = 1; off < 64; off <<= 1){
    float n = __shfl_up(sc, off, 64);
    if (lane >= off) sc += n;
  }
  __shared__ float wsum[4];
  if (lane == 63) wsum[wave] = sc;
  __syncthreads();
  float base = sc - tot;
  for (int w = 0; w < wave; ++w) base += wsum[w];
  #pragma unroll
  for (int i = 0; i < 4; i++){
    float th = base + v[i];
    float s, c;
    __sincosf(th, &s, &c);
    int t = t0 + i;
    cosb[(size_t)t * 1024 + h * 32 + k] = c;
    sinb[(size_t)t * 1024 + h * 32 + k] = s;
  }
}

// ---- rmsnorm + bias + rope -> Bb/Cb bf16 [t][h*128+n], 4-wide packed stores ----
__global__ __launch_bounds__(256) void bc_kernel(const float* __restrict__ proj,
                                                 const float* __restrict__ B_bias, const float* __restrict__ C_bias,
                                                 const float* __restrict__ Bn_w, const float* __restrict__ Cn_w,
                                                 const float* __restrict__ cosb, const float* __restrict__ sinb,
                                                 short* __restrict__ Bb, short* __restrict__ Cb){
  int t = blockIdx.x;
  int tid = threadIdx.x;
  __shared__ float vv[2][128];
  __shared__ float red[4];
  int n = tid & 127;
  int isC = tid >> 7;
  float val = proj[(size_t)t * DPROJ + 4096 + isC * 128 + n];
  float ss = val * val;
  #pragma unroll
  for (int off = 32; off >= 1; off >>= 1) ss += __shfl_down(ss, off);
  int wave = tid >> 6, lane = tid & 63;
  if (lane == 0) red[wave] = ss;
  __syncthreads();
  float rsv = isC ? rsqrtf((red[2] + red[3]) * (1.f / 128.f) + 1e-5f)
                  : rsqrtf((red[0] + red[1]) * (1.f / 128.f) + 1e-5f);
  vv[isC][n] = val * rsv * (isC ? Cn_w[n] : Bn_w[n]);
  __syncthreads();
  const float* cb = cosb + (size_t)t * 1024;
  const float* sb = sinb + (size_t)t * 1024;
  #pragma unroll
  for (int it = 0; it < 8; it++){
    int task = tid + 256 * it;        // 0..2047
    int arr  = task >> 10;            // 0=B, 1=C
    int rem  = task & 1023;
    int h    = rem >> 5;
    int n0   = (rem & 31) * 4;
    const float* bias = arr ? C_bias : B_bias;
    const float* base = vv[arr];
    f4 bv = *(const f4*)&base[n0];
    f4 bi = *(const f4*)&bias[h * 128 + n0];
    f4 o;
    if (n0 < 32){
      f4 bv2 = *(const f4*)&base[n0 + 32];
      f4 bi2 = *(const f4*)&bias[h * 128 + n0 + 32];
      f4 cv = *(const f4*)&cb[h * 32 + n0];
      f4 sv = *(const f4*)&sb[h * 32 + n0];
      #pragma unroll
      for (int q = 0; q < 4; q++) o[q] = (bv[q] + bi[q]) * cv[q] - (bv2[q] + bi2[q]) * sv[q];
    } else if (n0 < 64){
      int k0 = n0 - 32;
      f4 bv1 = *(const f4*)&base[k0];
      f4 bi1 = *(const f4*)&bias[h * 128 + k0];
      f4 cv = *(const f4*)&cb[h * 32 + k0];
      f4 sv = *(const f4*)&sb[h * 32 + k0];
      #pragma unroll
      for (int q = 0; q < 4; q++) o[q] = (bv1[q] + bi1[q]) * sv[q] + (bv[q] + bi[q]) * cv[q];
    } else {
      #pragma unroll
      for (int q = 0; q < 4; q++) o[q] = bv[q] + bi[q];
    }
    uint2 pk; pk.x = pack2(o.x, o.y); pk.y = pack2(o.z, o.w);
    short* outp = arr ? Cb : Bb;
    *(uint2*)(outp + (size_t)t * 4096 + h * 128 + n0) = pk;
  }
}

// ---- per-chunk state contribution, MFMA form (verified R3) ----
__global__ __launch_bounds__(256) void hpart_kernel(const short* __restrict__ xTb, const short* __restrict__ Bb,
                                                    const float* __restrict__ Lcum, const float* __restrict__ u2b,
                                                    short* __restrict__ Hpart){
  int h = blockIdx.x >> 3, c = blockIdx.x & 7;
  int t0 = c * 128;
  int tid = threadIdx.x;
  __shared__ float wS[128];
  if (tid < 128){
    float Lend = Lcum[h * 1024 + t0 + 127];
    wS[tid] = __expf(Lend - Lcum[h * 1024 + t0 + tid]) * u2b[h * 1024 + t0 + tid];
  }
  __syncthreads();
  int wave = tid >> 6, lane = tid & 63, quad = lane >> 4, r16 = lane & 15;
  int n0 = wave * 32;
  f4 acc[4][2];
  #pragma unroll
  for (int i = 0; i < 4; i++)
    #pragma unroll
    for (int j = 0; j < 2; j++) acc[i][j] = (f4){0.f, 0.f, 0.f, 0.f};

  const ushort* Bh = (const ushort*)Bb + (size_t)t0 * 4096 + h * 128;
  #pragma unroll
  for (int kk = 0; kk < 4; ++kk){
    int sb = kk * 32 + quad * 8;
    short8 af[4];
    #pragma unroll
    for (int i = 0; i < 4; i++){
      int p = i * 16 + r16;
      af[i] = *(const short8*)(xTb + (size_t)(h * 64 + p) * 1024 + t0 + sb);
    }
    float wv[8];
    #pragma unroll
    for (int jj = 0; jj < 8; jj++) wv[jj] = wS[sb + jj];
    short8 bfr[2];
    #pragma unroll
    for (int j = 0; j < 2; j++){
      int nn = n0 + j * 16 + r16;
      float e[8];
      #pragma unroll
      for (int jj = 0; jj < 8; jj++)
        e[jj] = b2f(Bh[(size_t)(sb + jj) * 4096 + nn]) * wv[jj];
      union { short8 s; uint32_t u[4]; } fr;
      #pragma unroll
      for (int q = 0; q < 4; q++) fr.u[q] = pack2(e[2 * q], e[2 * q + 1]);
      bfr[j] = fr.s;
    }
    #pragma unroll
    for (int i = 0; i < 4; i++)
      #pragma unroll
      for (int j = 0; j < 2; j++)
        acc[i][j] = __builtin_amdgcn_mfma_f32_16x16x32_bf16(af[i], bfr[j], acc[i][j], 0, 0, 0);
  }

  short* out = Hpart + ((size_t)(h * 8 + c)) * 8192;
  #pragma unroll
  for (int i = 0; i < 4; i++)
    #pragma unroll
    for (int rr = 0; rr < 4; ++rr){
      int p = i * 16 + quad * 4 + rr;
      #pragma unroll
      for (int j = 0; j < 2; j++){
        int nn = n0 + j * 16 + r16;
        out[p * 128 + nn] = f2b(acc[i][j][rr]);
      }
    }
}

// ---- 8-step state prefix: Hused[h][c] = H̃_{c-1} (bf16) ----
__global__ __launch_bounds__(256) void hscan_kernel(const short* __restrict__ Hpart,
                                                    const float* __restrict__ Lcum,
                                                    short* __restrict__ Hused){
  int idx = blockIdx.x * 256 + threadIdx.x;
  int h = idx >> 13, rem = idx & 8191;
  float acc = 0.f;
  float Lprev = 0.f;
  #pragma unroll
  for (int c = 0; c < 8; c++){
    Hused[((size_t)(h * 8 + c)) * 8192 + rem] = f2b(acc);
    float Lend = Lcum[h * 1024 + c * 128 + 127];
    float dec = __expf(Lend - Lprev);
    acc = dec * acc + b2f((uint16_t)Hpart[((size_t)(h * 8 + c)) * 8192 + rem]);
    Lprev = Lend;
  }
}

// ---- chunked dual: per (h,c): S=C@Bᵀ -> weight -> Y = G@X + ei·(C@H̃ᵀ); fused D/silu epilogue -> yb16 ----
#define GS 144
__global__ __launch_bounds__(256) void chunky_kernel(const short* __restrict__ Cb, const short* __restrict__ Bbg,
                                                     const short* __restrict__ xTb, const short* __restrict__ Hused,
                                                     const float* __restrict__ Lcum, const float* __restrict__ u2b,
                                                     const float* __restrict__ c1b,
                                                     const float* __restrict__ proj, const float* __restrict__ D_par,
                                                     short* __restrict__ yb16){
  int h = blockIdx.x >> 3, c = blockIdx.x & 7;
  int t0 = c * 128;
  __shared__ __align__(16) short Gt[128 * GS];
  __shared__ float Lc[128], u2v[128], c1v[128];
  int tid = threadIdx.x;
  if (tid < 128){
    Lc[tid]  = Lcum[h * 1024 + t0 + tid];
    u2v[tid] = u2b[h * 1024 + t0 + tid];
    c1v[tid] = c1b[h * 1024 + t0 + tid];
  }
  float Lprev = (c > 0) ? Lcum[h * 1024 + t0 - 1] : 0.f;
  float Dp = D_par[h];
  int wave = tid >> 6, lane = tid & 63, quad = lane >> 4, r16 = lane & 15;
  int wm = (wave >> 1) * 64, wn = (wave & 1) * 64;

  f4 acc[4][4];
  #pragma unroll
  for (int i = 0; i < 4; i++)
    #pragma unroll
    for (int j = 0; j < 4; j++) acc[i][j] = (f4){0.f, 0.f, 0.f, 0.f};
  #pragma unroll
  for (int kk = 0; kk < 4; ++kk){
    short8 af[4], bf[4];
    #pragma unroll
    for (int i = 0; i < 4; i++)
      af[i] = *(const short8*)(Cb + (size_t)(t0 + wm + i * 16 + r16) * 4096 + h * 128 + kk * 32 + quad * 8);
    #pragma unroll
    for (int j = 0; j < 4; j++)
      bf[j] = *(const short8*)(Bbg + (size_t)(t0 + wn + j * 16 + r16) * 4096 + h * 128 + kk * 32 + quad * 8);
    #pragma unroll
    for (int i = 0; i < 4; i++)
      #pragma unroll
      for (int j = 0; j < 4; j++)
        acc[i][j] = __builtin_amdgcn_mfma_f32_16x16x32_bf16(af[i], bf[j], acc[i][j], 0, 0, 0);
  }
  __syncthreads();

  #pragma unroll
  for (int i = 0; i < 4; i++){
    #pragma unroll
    for (int rr = 0; rr < 4; ++rr){
      int trow = wm + i * 16 + quad * 4 + rr;
      float Lt = Lc[trow];
      #pragma unroll
      for (int j = 0; j < 4; j++){
        int scol = wn + j * 16 + r16;
        float g = 0.f;
        if (scol <= trow){
          float wcoef = (scol == trow) ? c1v[scol] : u2v[scol];
          g = acc[i][j][rr] * wcoef * __expf(Lt - Lc[scol]);
        }
        Gt[trow * GS + scol] = f2b(g);
      }
    }
  }
  __syncthreads();

  f4 accY[2][4], accZ[2][4];
  #pragma unroll
  for (int i = 0; i < 2; i++)
    #pragma unroll
    for (int j = 0; j < 4; j++){ accY[i][j] = (f4){0.f,0.f,0.f,0.f}; accZ[i][j] = (f4){0.f,0.f,0.f,0.f}; }
  int m0 = wave * 32;
  #pragma unroll
  for (int kk = 0; kk < 4; ++kk){
    short8 ag[2], ac[2], bx[4], bh[4];
    #pragma unroll
    for (int i = 0; i < 2; i++){
      ag[i] = *(const short8*)&Gt[(m0 + i * 16 + r16) * GS + kk * 32 + quad * 8];
      ac[i] = *(const short8*)(Cb + (size_t)(t0 + m0 + i * 16 + r16) * 4096 + h * 128 + kk * 32 + quad * 8);
    }
    #pragma unroll
    for (int j = 0; j < 4; j++){
      bx[j] = *(const short8*)(xTb + (size_t)(h * 64 + j * 16 + r16) * 1024 + t0 + kk * 32 + quad * 8);
      bh[j] = *(const short8*)(Hused + ((size_t)(h * 8 + c) * 64 + j * 16 + r16) * 128 + kk * 32 + quad * 8);
    }
    #pragma unroll
    for (int i = 0; i < 2; i++)
      #pragma unroll
      for (int j = 0; j < 4; j++){
        accY[i][j] = __builtin_amdgcn_mfma_f32_16x16x32_bf16(ag[i], bx[j], accY[i][j], 0, 0, 0);
        accZ[i][j] = __builtin_amdgcn_mfma_f32_16x16x32_bf16(ac[i], bh[j], accZ[i][j], 0, 0, 0);
      }
  }
  // fused post: y = (y + D*x) * silu(z), cast bf16
  #pragma unroll
  for (int i = 0; i < 2; i++)
    #pragma unroll
    for (int rr = 0; rr < 4; ++rr){
      int trow = m0 + i * 16 + quad * 4 + rr;
      float ei = __expf(Lc[trow] - Lprev);
      const float* prow = proj + (size_t)(t0 + trow) * DPROJ;
      #pragma unroll
      for (int j = 0; j < 4; j++){
        int col = h * 64 + j * 16 + r16;
        float zv = prow[col];
        float xv = prow[2048 + col];
        float yv = accY[i][j][rr] + ei * accZ[i][j][rr] + Dp * xv;
        float o = yv * (zv / (1.f + __expf(-zv)));
        yb16[(size_t)(t0 + trow) * 2048 + col] = f2b(o);
      }
    }
}

extern "C" void kernel_launch(void* const* d_in, const int* in_sizes, int n_in,
                              void* d_out, int out_size, void* d_ws, size_t ws_size,
                              hipStream_t stream){
  const float* u       = (const float*)d_in[0];
  const float* W_in    = (const float*)d_in[1];
  const float* dt_bias = (const float*)d_in[2];
  const float* B_bias  = (const float*)d_in[3];
  const float* C_bias  = (const float*)d_in[4];
  const float* Bn_w    = (const float*)d_in[5];
  const float* Cn_w    = (const float*)d_in[6];
  const float* D_par   = (const float*)d_in[7];
  const float* W_out   = (const float*)d_in[8];
  float* out = (float*)d_out;

  char* ws = (char*)d_ws;
  short* u16   = (short*)(ws + 0);          //  2,097,152
  short* WtIn  = (short*)(ws + 2097152);    //  9,175,040  [4480][1024] bf16
  short* WtOut = (short*)(ws + 11272192);   //  4,194,304  [1024][2048] bf16
  float* proj  = (float*)(ws + 15466496);   // 18,350,080  [1024][4480] fp32
  float* cosb  = (float*)(ws + 33816576);   //  4,194,304  [1024][1024]
  float* sinb  = (float*)(ws + 38010880);   //  4,194,304
  short* Bb    = (short*)(ws + 42205184);   //  8,388,608  [1024][4096] bf16
  short* Cb    = (short*)(ws + 50593792);   //  8,388,608
  short* xTb   = (short*)(ws + 58982400);   //  4,194,304  [2048][1024] bf16
  float* Lcum  = (float*)(ws + 63176704);   //    131,072  [32][1024]
  float* u2b   = (float*)(ws + 63307776);   //    131,072
  float* c1b   = (float*)(ws + 63438848);   //    131,072
  float* dtb   = (float*)(ws + 63569920);   //    131,072
  short* Hpart = (short*)(ws + 63700992);   //  4,194,304  [32][8][64][128] bf16
  short* Hused = (short*)(ws + 67895296);   //  4,194,304
  short* yb16  = (short*)(ws + 72089600);   //  4,194,304  -> total 76,283,904 B

  hipMemsetAsync(out, 0, (size_t)out_size * sizeof(float), stream);
  cast_kernel<<<1024, 256, 0, stream>>>(u, u16);
  transpose_cast<<<dim3(140, 8), 256, 0, stream>>>(W_in, WtIn, 1024, 4480, 4480, 0);
  transpose_cast<<<dim3(32, 16), 256, 0, stream>>>(W_out, WtOut, 2048, 1024, 1024, 0);
  gemm1_kernel<<<dim3(28, 8), 256, 0, stream>>>(u16, WtIn, proj);
  scanL_kernel<<<32, 256, 0, stream>>>(proj, dt_bias, Lcum, u2b, c1b, dtb);
  theta2_kernel<<<1024, 256, 0, stream>>>(proj, dtb, cosb, sinb);
  bc_kernel<<<1024, 256, 0, stream>>>(proj, B_bias, C_bias, Bn_w, Cn_w, cosb, sinb, Bb, Cb);
  transpose_cast<<<dim3(64, 8), 256, 0, stream>>>(proj, xTb, 1024, 2048, 4480, 2048);
  hpart_kernel<<<256, 256, 0, stream>>>(xTb, Bb, Lcum, u2b, Hpart);
  hscan_kernel<<<1024, 256, 0, stream>>>(Hpart, Lcum, Hused);
  chunky_kernel<<<256, 256, 0, stream>>>(Cb, Bb, xTb, Hused, Lcum, u2b, c1b, proj, D_par, yb16);
  gemm2_kernel<<<dim3(8, 8, 4), 256, 0, stream>>>(yb16, WtOut, out);
}